// Round 6
// baseline (201.467 us; speedup 1.0000x reference)
//
#include <hip/hip_runtime.h>
#include <cstdint>
#include <cstddef>

#define BATCH 8
#define FHh   32
#define FWw   256
#define NA    6
#define NANCH (FHh * FWw * NA)   // 49152
#define PRE_K 2000
#define POST_K 300
#define NBIN  65536
#define SEGS  192                // blocks per batch in k_gather (NANCH/256)
#define SKEYN 4096
#define SORT_T 256
#define ELEMS  16                // elements per thread in k_sortdec

typedef unsigned long long u64;

// ---------------- workspace layout (bytes), total 5,675,520 ----------------
#define WS_SC   0
#define WS_PB   0
#define WS_PS   256000
#define WS_A    1572864
#define WS_CNT  5668864
#define WS_CUT  5675008

// ---------------- K0: zero histogram ----------------
__global__ void k_zero(unsigned int* __restrict__ hist) {
    int g = blockIdx.x * blockDim.x + threadIdx.x;
    if (g < BATCH * NBIN) hist[g] = 0u;
}

// ---------------- K1: fused softmax + 16-bit-key histogram ----------------
__global__ void k_softhist(const float* __restrict__ labels, float* __restrict__ scores,
                           unsigned int* __restrict__ hist) {
    int pos = blockIdx.x * blockDim.x + threadIdx.x;  // over BATCH*FH*FW
    if (pos >= BATCH * FHh * FWw) return;
    int b = pos / (FHh * FWw);
    const float2* in2 = (const float2*)(labels + (size_t)pos * NA);
    float v[NA];
    float2 p0 = in2[0], p1 = in2[1], p2 = in2[2];
    v[0] = p0.x; v[1] = p0.y; v[2] = p1.x; v[3] = p1.y; v[4] = p2.x; v[5] = p2.y;
    float m = v[0];
#pragma unroll
    for (int a = 1; a < NA; ++a) m = fmaxf(m, v[a]);
    float s = 0.0f;
#pragma unroll
    for (int a = 0; a < NA; ++a) { v[a] = expf(v[a] - m); s += v[a]; }
    float inv = 1.0f / s;
    float2* o2 = (float2*)(scores + (size_t)pos * NA);
    unsigned int* hb = hist + (size_t)b * NBIN;
#pragma unroll
    for (int a = 0; a < NA; ++a) v[a] *= inv;
    o2[0] = make_float2(v[0], v[1]);
    o2[1] = make_float2(v[2], v[3]);
    o2[2] = make_float2(v[4], v[5]);
#pragma unroll
    for (int a = 0; a < NA; ++a)
        atomicAdd(&hb[__float_as_uint(v[a]) >> 16], 1u);  // fire-and-forget
}

// ---------------- K2: per-batch find 16-bit cutoff bin ----------------
__global__ __launch_bounds__(1024) void k_cut(const unsigned int* __restrict__ hist,
                                              unsigned int* __restrict__ cut) {
    const int b = blockIdx.x;
    const int tid = threadIdx.x;
    const unsigned int* h = hist + (size_t)b * NBIN;
    // this thread's contiguous aligned 64-bin block: [blk0, blk0+64)
    const int blk0 = NBIN - 64 * (tid + 1);
    const uint4* h4 = (const uint4*)(h + blk0);
    unsigned int s = 0;
#pragma unroll
    for (int k = 0; k < 16; ++k) {
        uint4 q = h4[k];
        s += q.x + q.y + q.z + q.w;
    }
    const int lane = tid & 63, wid = tid >> 6;
    unsigned int inc = s;
#pragma unroll
    for (int d = 1; d < 64; d <<= 1) {
        unsigned int v = __shfl_up(inc, d);
        if (lane >= d) inc += v;
    }
    __shared__ unsigned int wtot[16];
    if (lane == 63) wtot[wid] = inc;
    __syncthreads();
    unsigned int woff = 0;
    for (int w = 0; w < 16; ++w) if (w < wid) woff += wtot[w];
    unsigned int excl = woff + inc - s;  // count strictly above this block
    if (excl < PRE_K && excl + s >= PRE_K) {
        const int base = NBIN - 1 - tid * 64;  // top bin of the block
        unsigned int run = excl;
        for (int k = 0; k < 64; ++k) {
            run += h[base - k];
            if (run >= PRE_K) { cut[b * 16] = (unsigned int)(base - k); break; }
        }
    }
}

// ------- K3: atomic-free gather. block = (batch b, segment kb of 256 anchors) -
__global__ __launch_bounds__(256) void k_gather(
        const float* __restrict__ scores, const unsigned int* __restrict__ cut,
        u64* __restrict__ cand, unsigned int* __restrict__ counts) {
    const int blk = blockIdx.x;
    const int b = blk / SEGS, kb = blk - b * SEGS;
    const int tid = threadIdx.x;
    __shared__ unsigned int s_cut;
    __shared__ unsigned int s_wcnt[4];
    if (tid == 0) s_cut = cut[b * 16];
    __syncthreads();
    const int idx = kb * 256 + tid;                       // batch-local anchor
    const unsigned int bits = __float_as_uint(scores[(size_t)b * NANCH + idx]);
    const bool pass = (bits >> 16) >= s_cut;
    const u64 m = __ballot(pass);
    const int lane = tid & 63, w = tid >> 6;
    if (lane == 0) s_wcnt[w] = (unsigned int)__popcll(m);
    __syncthreads();
    unsigned int pre = 0, tot = 0;
#pragma unroll
    for (int i = 0; i < 4; ++i) { unsigned int c = s_wcnt[i]; if (i < w) pre += c; tot += c; }
    if (pass) {
        unsigned int rank = pre + (unsigned int)__popcll(m & ((1ull << lane) - 1ull));
        cand[((size_t)b * SEGS + kb) * 256 + rank] =
            ((u64)bits << 32) | (unsigned int)(~idx);
    }
    if (tid == 0) counts[b * SEGS + kb] = tot;
}

// ---- K4: register-resident bitonic sort of 4096 + decode top-2000 ----------
// 256 threads x 16 contiguous elements. Stages j<16 in registers; j>=16 via
// LDS chunk exchange (elementwise min/max, no idle threads).
__global__ __launch_bounds__(SORT_T) void k_sortdec(
        const u64* __restrict__ cand, const unsigned int* __restrict__ counts,
        const float* __restrict__ deltas, const float* __restrict__ anchors,
        float4* __restrict__ pre_boxes, float* __restrict__ pre_scores) {
    const int b = blockIdx.x;
    const int tid = threadIdx.x;
    __shared__ u64 skey[SKEYN];
    __shared__ unsigned int s_wsum[4];
    for (int i = tid; i < SKEYN; i += SORT_T) skey[i] = 0ull;

    // scan the 192 per-segment counts (4 waves; only first 3 carry data)
    unsigned int v = (tid < SEGS) ? counts[b * SEGS + tid] : 0u;
    const int lane = tid & 63, wid = tid >> 6;
    unsigned int inc = v;
#pragma unroll
    for (int d = 1; d < 64; d <<= 1) {
        unsigned int t = __shfl_up(inc, d);
        if (lane >= d) inc += t;
    }
    if (lane == 63) s_wsum[wid] = inc;
    __syncthreads();
    if (tid < SEGS) {
        unsigned int woff = 0;
        for (int i = 0; i < wid; ++i) woff += s_wsum[i];
        unsigned int off = woff + inc - v;  // exclusive prefix
        const u64* seg = cand + ((size_t)b * SEGS + tid) * 256;
        for (unsigned int k = 0; k < v; ++k) {
            unsigned int p = off + k;
            if (p < SKEYN) skey[p] = seg[k];
        }
    }
    __syncthreads();

    // own chunk -> registers
    u64 r[ELEMS];
    const int base = tid * ELEMS;
#pragma unroll
    for (int e = 0; e < ELEMS; ++e) r[e] = skey[base + e];

    // ---- in-register levels k = 2..16 (all j < 16) ----
#pragma unroll
    for (int k = 2; k <= ELEMS; k <<= 1) {
#pragma unroll
        for (int j = ELEMS; j >= 1; j >>= 1) {
            if (j >= k) continue;  // j runs k/2..1
#pragma unroll
            for (int e = 0; e < ELEMS; ++e) {
                int pe = e ^ j;
                if (pe > e) {
                    bool desc = (((base + e) & k) == 0);
                    u64 a = r[e], c = r[pe];
                    if ((a < c) == desc) { r[e] = c; r[pe] = a; }
                }
            }
        }
    }

    // ---- levels k = 32..4096: cross-thread j>=16 via LDS, then j<16 in-reg --
    for (int k = 2 * ELEMS; k <= SKEYN; k <<= 1) {
        const bool desc = ((base & k) == 0);  // uniform per thread (k >= 32)
        for (int j = k >> 1; j >= ELEMS; j >>= 1) {
            __syncthreads();  // previous reads done before overwrite
#pragma unroll
            for (int e = 0; e < ELEMS; ++e) skey[base + e] = r[e];
            __syncthreads();
            const int pt = tid ^ (j / ELEMS);
            const bool low = (tid & (j / ELEMS)) == 0;
            const bool takeMax = (low == desc);
            const u64* pk = &skey[pt * ELEMS];
#pragma unroll
            for (int e = 0; e < ELEMS; ++e) {
                u64 o = pk[e];
                u64 a = r[e];
                r[e] = takeMax ? (a > o ? a : o) : (a < o ? a : o);
            }
        }
#pragma unroll
        for (int j = ELEMS / 2; j >= 1; j >>= 1) {
#pragma unroll
            for (int e = 0; e < ELEMS; ++e) {
                int pe = e ^ j;
                if (pe > e) {
                    u64 a = r[e], c = r[pe];
                    if ((a < c) == desc) { r[e] = c; r[pe] = a; }
                }
            }
        }
    }

    // write back sorted keys, then decode top-2000 strided
    __syncthreads();
#pragma unroll
    for (int e = 0; e < ELEMS; ++e) skey[base + e] = r[e];
    __syncthreads();

    for (int t = tid; t < PRE_K; t += SORT_T) {
        u64 key = skey[t];
        int idx = (int)(~(unsigned int)key);
        float score = __uint_as_float((unsigned int)(key >> 32));
        const float* anc = anchors + (size_t)idx * 4;
        const float* del = deltas + ((size_t)b * NANCH + idx) * 4;
        float a0 = anc[0], a1 = anc[1], a2 = anc[2], a3 = anc[3];
        float ah = a2 - a0, aw = a3 - a1;
        float acy = a0 + 0.5f * ah, acx = a1 + 0.5f * aw;
        float d0 = del[0] * 0.1f, d1 = del[1] * 0.1f;
        float d2 = del[2] * 0.2f, d3 = del[3] * 0.2f;
        float bh = expf(d2) * ah, bw = expf(d3) * aw;
        float bcy = d0 * ah + acy, bcx = d1 * aw + acx;
        float y1 = bcy - 0.5f * bh, x1 = bcx - 0.5f * bw;
        pre_boxes[(size_t)b * PRE_K + t] = make_float4(y1, x1, y1 + bh, x1 + bw);
        pre_scores[(size_t)b * PRE_K + t] = score;
    }
}

// ---------------- K5: suppression bit-matrix (LDS-staged cols) ----------------
__global__ __launch_bounds__(64) void k_iou(const float4* __restrict__ pre_boxes,
                                            u64* __restrict__ supp) {
    const int cb = blockIdx.x;   // col word 0..31
    const int rb = blockIdx.y;   // row block 0..31
    const int b  = blockIdx.z;
    const int lane = threadIdx.x;
    const int i = rb * 64 + lane;
    const int j0 = cb * 64;
    if (cb < rb) {
        if (i < PRE_K) supp[((size_t)b * PRE_K + i) * 32 + cb] = 0ull;
        return;
    }
    __shared__ float4 sbox[64];
    const float4* boxes = pre_boxes + (size_t)b * PRE_K;
    int j = j0 + lane;
    sbox[lane] = (j < PRE_K) ? boxes[j] : make_float4(0.f, 0.f, 0.f, 0.f);
    __syncthreads();
    if (i >= PRE_K) return;
    float4 bi = boxes[i];
    float area_i = (bi.z - bi.x) * (bi.w - bi.y);
    u64 bits = 0ull;
    const int tmax = (PRE_K - j0 < 64) ? (PRE_K - j0) : 64;
    for (int t = 0; t < tmax; ++t) {
        int jj = j0 + t;
        if (jj <= i) continue;
        float4 bj = sbox[t];
        float iy1 = fmaxf(bi.x, bj.x), ix1 = fmaxf(bi.y, bj.y);
        float iy2 = fminf(bi.z, bj.z), ix2 = fminf(bi.w, bj.w);
        float inter = fmaxf(iy2 - iy1, 0.0f) * fmaxf(ix2 - ix1, 0.0f);
        float area_j = (bj.z - bj.x) * (bj.w - bj.y);
        float uni = area_i + area_j - inter;
        float iou = inter / fmaxf(uni, 1e-8f);
        if (iou > 0.7f) bits |= (1ull << t);
    }
    supp[((size_t)b * PRE_K + i) * 32 + cb] = bits;
}

// ---------------- K6: serial greedy reduce + compact + outputs ----------------
__device__ __forceinline__ u64 readlane64(u64 x, int ln) {
    unsigned int lo = __builtin_amdgcn_readlane((unsigned int)x, ln);
    unsigned int hi = __builtin_amdgcn_readlane((unsigned int)(x >> 32), ln);
    return ((u64)hi << 32) | (u64)lo;
}

template <int NR>
__device__ __forceinline__ void load_chunk(u64* __restrict__ buf,
        const u64* __restrict__ S, int base, int lw) {
#pragma unroll
    for (int c = 0; c < NR; ++c)
        buf[c] = S[(size_t)(base + c) * 32 + lw];
}

template <int NR>
__device__ __forceinline__ void process_chunk(const u64* __restrict__ buf,
        int wi, u64& r0, u64& r1, u64& cur) {
    cur = ~readlane64(r0 | r1, wi);
#pragma unroll
    for (int g = 0; g < NR / 16; ++g) {
        const int b0 = g * 16;
        u64 t0 = (buf[b0+0] | buf[b0+1]) | (buf[b0+2] | buf[b0+3]);
        u64 t1 = (buf[b0+4] | buf[b0+5]) | (buf[b0+6] | buf[b0+7]);
        u64 t2 = (buf[b0+8] | buf[b0+9]) | (buf[b0+10] | buf[b0+11]);
        u64 t3 = (buf[b0+12] | buf[b0+13]) | (buf[b0+14] | buf[b0+15]);
        u64 tor = (t0 | t1) | (t2 | t3);
        u64 intra = readlane64(tor, wi);
        if (intra == 0ull) {
#pragma unroll
            for (int c = 0; c < 16; ++c) {
                u64 msk = ((cur >> (b0 + c)) & 1ull) ? ~0ull : 0ull;
                if (c & 1) r1 |= buf[b0+c] & msk; else r0 |= buf[b0+c] & msk;
            }
        } else {
#pragma unroll
            for (int c = 0; c < 16; ++c) {
                if ((cur >> (b0 + c)) & 1ull) {
                    cur &= ~readlane64(buf[b0+c], wi);
                    if (c & 1) r1 |= buf[b0+c]; else r0 |= buf[b0+c];
                }
            }
        }
    }
}

__global__ __launch_bounds__(64) void k_final(const u64* __restrict__ supp,
                        const float4* __restrict__ pre_boxes,
                        const float* __restrict__ pre_scores,
                        float* __restrict__ out) {
    const int b = blockIdx.x;
    const int lane = threadIdx.x;
    float* ob = out + (size_t)b * POST_K * 4;
    float* os = out + (size_t)BATCH * POST_K * 4 + (size_t)b * POST_K;
    for (int t = lane; t < POST_K * 4; t += 64) ob[t] = 0.0f;
    for (int t = lane; t < POST_K; t += 64) os[t] = 0.0f;

    const u64* S = supp + (size_t)b * PRE_K * 32;
    const int lw = lane & 31;
    u64 r0 = 0ull, r1 = 0ull, cur = ~0ull;
    u64 A[64], B[64];
    load_chunk<64>(A, S, 0, lw);
    for (int ch = 0; ch < 30; ch += 2) {
        load_chunk<64>(B, S, (ch + 1) * 64, lw);
        process_chunk<64>(A, ch, r0, r1, cur);
        load_chunk<64>(A, S, (ch + 2) * 64, lw);
        process_chunk<64>(B, ch + 1, r0, r1, cur);
    }
    load_chunk<16>(B, S, 31 * 64, lw);
    process_chunk<64>(A, 30, r0, r1, cur);
    process_chunk<16>(B, 31, r0, r1, cur);
    const u64 removed = r0 | r1;

    u64 kw = ~removed;
    if (lw == 31) kw &= 0xFFFFull;  // rows 1984..1999 only
    int cnt = (lane < 32) ? __builtin_popcountll(kw) : 0;
    int cum = cnt;
#pragma unroll
    for (int d = 1; d < 64; d <<= 1) {
        int v = __shfl_up(cum, d);
        if (lane >= d) cum += v;
    }
    int r = cum - cnt;
    __syncthreads();
    if (lane < 32) {
        u64 m = kw;
        while (m != 0ull && r < POST_K) {
            int t = __builtin_ctzll(m);
            m &= m - 1ull;
            int i = lw * 64 + t;
            float4 bx = pre_boxes[(size_t)b * PRE_K + i];
            ob[r * 4 + 0] = fminf(fmaxf(bx.x, 0.0f), 1.0f);
            ob[r * 4 + 1] = fminf(fmaxf(bx.y, 0.0f), 1.0f);
            ob[r * 4 + 2] = fminf(fmaxf(bx.z, 0.0f), 1.0f);
            ob[r * 4 + 3] = fminf(fmaxf(bx.w, 0.0f), 1.0f);
            os[r] = pre_scores[(size_t)b * PRE_K + i];
            ++r;
        }
    }
}

extern "C" void kernel_launch(void* const* d_in, const int* in_sizes, int n_in,
                              void* d_out, int out_size, void* d_ws, size_t ws_size,
                              hipStream_t stream) {
    const float* deltas  = (const float*)d_in[0];
    const float* labels  = (const float*)d_in[1];
    const float* anchors = (const float*)d_in[2];
    float* out = (float*)d_out;

    char* ws = (char*)d_ws;
    float* scores          = (float*)(ws + WS_SC);
    unsigned int* hist     = (unsigned int*)(ws + WS_A);
    u64* cd                = (u64*)(ws + WS_A);   // reuses hist
    u64* sp                = (u64*)(ws + WS_A);   // reuses cand
    unsigned int* cntp     = (unsigned int*)(ws + WS_CNT);
    unsigned int* cutp     = (unsigned int*)(ws + WS_CUT);
    float4* pre_boxes      = (float4*)(ws + WS_PB);              // reuses scores
    float* pre_scores      = (float*)(ws + WS_PS);

    k_zero<<<(BATCH * NBIN + 255) / 256, 256, 0, stream>>>(hist);
    k_softhist<<<(BATCH * FHh * FWw + 255) / 256, 256, 0, stream>>>(labels, scores, hist);
    k_cut<<<BATCH, 1024, 0, stream>>>(hist, cutp);
    k_gather<<<BATCH * SEGS, 256, 0, stream>>>(scores, cutp, cd, cntp);
    k_sortdec<<<BATCH, SORT_T, 0, stream>>>(cd, cntp, deltas, anchors, pre_boxes, pre_scores);
    k_iou<<<dim3(32, 32, BATCH), 64, 0, stream>>>(pre_boxes, sp);
    k_final<<<BATCH, 64, 0, stream>>>(sp, pre_boxes, pre_scores, out);
}

// Round 7
// 172.589 us; speedup vs baseline: 1.1673x; 1.1673x over previous
//
#include <hip/hip_runtime.h>
#include <cstdint>
#include <cstddef>

#define BATCH 8
#define FHh   32
#define FWw   256
#define NA    6
#define NANCH (FHh * FWw * NA)   // 49152
#define PRE_K 2000
#define POST_K 300
#define NBIN  65536
#define SEGS  192                // blocks per batch in k_gather (NANCH/256)
#define SKEYN 4096
#define SORT_T 256
#define ELEMS  16                // elements per thread in k_sortdec
// padded LDS index: +1 u64 per 16 -> per-thread stride 17 (odd) kills the
// 32-way bank conflict of the 128B-stride chunk layout (r6: 797K conflicts)
#define SK(i) ((i) + ((i) >> 4))
#define SKPAD (SKEYN + (SKEYN >> 4))   // 4352

typedef unsigned long long u64;

// ---------------- workspace layout (bytes), total 5,675,520 ----------------
#define WS_SC   0
#define WS_PB   0
#define WS_PS   256000
#define WS_A    1572864
#define WS_CNT  5668864
#define WS_CUT  5675008

// ---------------- K0: zero histogram ----------------
__global__ void k_zero(unsigned int* __restrict__ hist) {
    int g = blockIdx.x * blockDim.x + threadIdx.x;
    if (g < BATCH * NBIN) hist[g] = 0u;
}

// ---------------- K1: fused softmax + 16-bit-key histogram ----------------
__global__ void k_softhist(const float* __restrict__ labels, float* __restrict__ scores,
                           unsigned int* __restrict__ hist) {
    int pos = blockIdx.x * blockDim.x + threadIdx.x;  // over BATCH*FH*FW
    if (pos >= BATCH * FHh * FWw) return;
    int b = pos / (FHh * FWw);
    const float2* in2 = (const float2*)(labels + (size_t)pos * NA);
    float v[NA];
    float2 p0 = in2[0], p1 = in2[1], p2 = in2[2];
    v[0] = p0.x; v[1] = p0.y; v[2] = p1.x; v[3] = p1.y; v[4] = p2.x; v[5] = p2.y;
    float m = v[0];
#pragma unroll
    for (int a = 1; a < NA; ++a) m = fmaxf(m, v[a]);
    float s = 0.0f;
#pragma unroll
    for (int a = 0; a < NA; ++a) { v[a] = expf(v[a] - m); s += v[a]; }
    float inv = 1.0f / s;
    float2* o2 = (float2*)(scores + (size_t)pos * NA);
    unsigned int* hb = hist + (size_t)b * NBIN;
#pragma unroll
    for (int a = 0; a < NA; ++a) v[a] *= inv;
    o2[0] = make_float2(v[0], v[1]);
    o2[1] = make_float2(v[2], v[3]);
    o2[2] = make_float2(v[4], v[5]);
#pragma unroll
    for (int a = 0; a < NA; ++a)
        atomicAdd(&hb[__float_as_uint(v[a]) >> 16], 1u);  // fire-and-forget
}

// ---------------- K2: per-batch find 16-bit cutoff bin ----------------
__global__ __launch_bounds__(1024) void k_cut(const unsigned int* __restrict__ hist,
                                              unsigned int* __restrict__ cut) {
    const int b = blockIdx.x;
    const int tid = threadIdx.x;
    const unsigned int* h = hist + (size_t)b * NBIN;
    const int blk0 = NBIN - 64 * (tid + 1);
    const uint4* h4 = (const uint4*)(h + blk0);
    unsigned int s = 0;
#pragma unroll
    for (int k = 0; k < 16; ++k) {
        uint4 q = h4[k];
        s += q.x + q.y + q.z + q.w;
    }
    const int lane = tid & 63, wid = tid >> 6;
    unsigned int inc = s;
#pragma unroll
    for (int d = 1; d < 64; d <<= 1) {
        unsigned int v = __shfl_up(inc, d);
        if (lane >= d) inc += v;
    }
    __shared__ unsigned int wtot[16];
    if (lane == 63) wtot[wid] = inc;
    __syncthreads();
    unsigned int woff = 0;
    for (int w = 0; w < 16; ++w) if (w < wid) woff += wtot[w];
    unsigned int excl = woff + inc - s;  // count strictly above this block
    if (excl < PRE_K && excl + s >= PRE_K) {
        const int base = NBIN - 1 - tid * 64;  // top bin of the block
        unsigned int run = excl;
        for (int k = 0; k < 64; ++k) {
            run += h[base - k];
            if (run >= PRE_K) { cut[b * 16] = (unsigned int)(base - k); break; }
        }
    }
}

// ------- K3: atomic-free gather. block = (batch b, segment kb of 256 anchors) -
__global__ __launch_bounds__(256) void k_gather(
        const float* __restrict__ scores, const unsigned int* __restrict__ cut,
        u64* __restrict__ cand, unsigned int* __restrict__ counts) {
    const int blk = blockIdx.x;
    const int b = blk / SEGS, kb = blk - b * SEGS;
    const int tid = threadIdx.x;
    __shared__ unsigned int s_cut;
    __shared__ unsigned int s_wcnt[4];
    if (tid == 0) s_cut = cut[b * 16];
    __syncthreads();
    const int idx = kb * 256 + tid;                       // batch-local anchor
    const unsigned int bits = __float_as_uint(scores[(size_t)b * NANCH + idx]);
    const bool pass = (bits >> 16) >= s_cut;
    const u64 m = __ballot(pass);
    const int lane = tid & 63, w = tid >> 6;
    if (lane == 0) s_wcnt[w] = (unsigned int)__popcll(m);
    __syncthreads();
    unsigned int pre = 0, tot = 0;
#pragma unroll
    for (int i = 0; i < 4; ++i) { unsigned int c = s_wcnt[i]; if (i < w) pre += c; tot += c; }
    if (pass) {
        unsigned int rank = pre + (unsigned int)__popcll(m & ((1ull << lane) - 1ull));
        cand[((size_t)b * SEGS + kb) * 256 + rank] =
            ((u64)bits << 32) | (unsigned int)(~idx);
    }
    if (tid == 0) counts[b * SEGS + kb] = tot;
}

// ---- K4: register-resident bitonic sort of 4096 + decode top-2000 ----------
// 256 threads x 16 contiguous elements; padded LDS (SK) for conflict-free
// chunk exchange. Stages j<16 in registers; j>=16 via LDS min/max exchange.
__global__ __launch_bounds__(SORT_T) void k_sortdec(
        const u64* __restrict__ cand, const unsigned int* __restrict__ counts,
        const float* __restrict__ deltas, const float* __restrict__ anchors,
        float4* __restrict__ pre_boxes, float* __restrict__ pre_scores) {
    const int b = blockIdx.x;
    const int tid = threadIdx.x;
    __shared__ u64 skey[SKPAD];
    __shared__ unsigned int s_wsum[4];
    for (int i = tid; i < SKPAD; i += SORT_T) skey[i] = 0ull;

    // scan the 192 per-segment counts (4 waves; only first 3 carry data)
    unsigned int v = (tid < SEGS) ? counts[b * SEGS + tid] : 0u;
    const int lane = tid & 63, wid = tid >> 6;
    unsigned int inc = v;
#pragma unroll
    for (int d = 1; d < 64; d <<= 1) {
        unsigned int t = __shfl_up(inc, d);
        if (lane >= d) inc += t;
    }
    if (lane == 63) s_wsum[wid] = inc;
    __syncthreads();
    if (tid < SEGS) {
        unsigned int woff = 0;
        for (int i = 0; i < wid; ++i) woff += s_wsum[i];
        unsigned int off = woff + inc - v;  // exclusive prefix
        const u64* seg = cand + ((size_t)b * SEGS + tid) * 256;
        for (unsigned int k = 0; k < v; ++k) {
            unsigned int p = off + k;
            if (p < SKEYN) skey[SK(p)] = seg[k];
        }
    }
    __syncthreads();

    // own chunk -> registers (stride-17 u64: conflict-free floor)
    u64 r[ELEMS];
    const int base = tid * ELEMS;
#pragma unroll
    for (int e = 0; e < ELEMS; ++e) r[e] = skey[SK(base + e)];

    // ---- in-register levels k = 2..16 (all j < 16) ----
#pragma unroll
    for (int k = 2; k <= ELEMS; k <<= 1) {
#pragma unroll
        for (int j = ELEMS; j >= 1; j >>= 1) {
            if (j >= k) continue;  // j runs k/2..1
#pragma unroll
            for (int e = 0; e < ELEMS; ++e) {
                int pe = e ^ j;
                if (pe > e) {
                    bool desc = (((base + e) & k) == 0);
                    u64 a = r[e], c = r[pe];
                    if ((a < c) == desc) { r[e] = c; r[pe] = a; }
                }
            }
        }
    }

    // ---- levels k = 32..4096: cross-thread j>=16 via LDS, then j<16 in-reg --
    for (int k = 2 * ELEMS; k <= SKEYN; k <<= 1) {
        const bool desc = ((base & k) == 0);  // uniform per thread (k >= 32)
        for (int j = k >> 1; j >= ELEMS; j >>= 1) {
            __syncthreads();  // previous reads done before overwrite
#pragma unroll
            for (int e = 0; e < ELEMS; ++e) skey[SK(base + e)] = r[e];
            __syncthreads();
            const int pt = tid ^ (j / ELEMS);
            const bool low = (tid & (j / ELEMS)) == 0;
            const bool takeMax = (low == desc);
            const int pbase = pt * ELEMS;
#pragma unroll
            for (int e = 0; e < ELEMS; ++e) {
                u64 o = skey[SK(pbase + e)];
                u64 a = r[e];
                r[e] = takeMax ? (a > o ? a : o) : (a < o ? a : o);
            }
        }
#pragma unroll
        for (int j = ELEMS / 2; j >= 1; j >>= 1) {
#pragma unroll
            for (int e = 0; e < ELEMS; ++e) {
                int pe = e ^ j;
                if (pe > e) {
                    u64 a = r[e], c = r[pe];
                    if ((a < c) == desc) { r[e] = c; r[pe] = a; }
                }
            }
        }
    }

    // write back sorted keys, then decode top-2000 strided
    __syncthreads();
#pragma unroll
    for (int e = 0; e < ELEMS; ++e) skey[SK(base + e)] = r[e];
    __syncthreads();

    for (int t = tid; t < PRE_K; t += SORT_T) {
        u64 key = skey[SK(t)];
        int idx = (int)(~(unsigned int)key);
        float score = __uint_as_float((unsigned int)(key >> 32));
        const float* anc = anchors + (size_t)idx * 4;
        const float* del = deltas + ((size_t)b * NANCH + idx) * 4;
        float a0 = anc[0], a1 = anc[1], a2 = anc[2], a3 = anc[3];
        float ah = a2 - a0, aw = a3 - a1;
        float acy = a0 + 0.5f * ah, acx = a1 + 0.5f * aw;
        float d0 = del[0] * 0.1f, d1 = del[1] * 0.1f;
        float d2 = del[2] * 0.2f, d3 = del[3] * 0.2f;
        float bh = expf(d2) * ah, bw = expf(d3) * aw;
        float bcy = d0 * ah + acy, bcx = d1 * aw + acx;
        float y1 = bcy - 0.5f * bh, x1 = bcx - 0.5f * bw;
        pre_boxes[(size_t)b * PRE_K + t] = make_float4(y1, x1, y1 + bh, x1 + bw);
        pre_scores[(size_t)b * PRE_K + t] = score;
    }
}

// ---------------- K5: suppression bit-matrix (LDS-staged cols) ----------------
__global__ __launch_bounds__(64) void k_iou(const float4* __restrict__ pre_boxes,
                                            u64* __restrict__ supp) {
    const int cb = blockIdx.x;   // col word 0..31
    const int rb = blockIdx.y;   // row block 0..31
    const int b  = blockIdx.z;
    const int lane = threadIdx.x;
    const int i = rb * 64 + lane;
    const int j0 = cb * 64;
    if (cb < rb) {
        if (i < PRE_K) supp[((size_t)b * PRE_K + i) * 32 + cb] = 0ull;
        return;
    }
    __shared__ float4 sbox[64];
    const float4* boxes = pre_boxes + (size_t)b * PRE_K;
    int j = j0 + lane;
    sbox[lane] = (j < PRE_K) ? boxes[j] : make_float4(0.f, 0.f, 0.f, 0.f);
    __syncthreads();
    if (i >= PRE_K) return;
    float4 bi = boxes[i];
    float area_i = (bi.z - bi.x) * (bi.w - bi.y);
    u64 bits = 0ull;
    const int tmax = (PRE_K - j0 < 64) ? (PRE_K - j0) : 64;
    for (int t = 0; t < tmax; ++t) {
        int jj = j0 + t;
        if (jj <= i) continue;
        float4 bj = sbox[t];
        float iy1 = fmaxf(bi.x, bj.x), ix1 = fmaxf(bi.y, bj.y);
        float iy2 = fminf(bi.z, bj.z), ix2 = fminf(bi.w, bj.w);
        float inter = fmaxf(iy2 - iy1, 0.0f) * fmaxf(ix2 - ix1, 0.0f);
        float area_j = (bj.z - bj.x) * (bj.w - bj.y);
        float uni = area_i + area_j - inter;
        float iou = inter / fmaxf(uni, 1e-8f);
        if (iou > 0.7f) bits |= (1ull << t);
    }
    supp[((size_t)b * PRE_K + i) * 32 + cb] = bits;
}

// ---------------- K6: serial greedy reduce + compact + outputs ----------------
__device__ __forceinline__ u64 readlane64(u64 x, int ln) {
    unsigned int lo = __builtin_amdgcn_readlane((unsigned int)x, ln);
    unsigned int hi = __builtin_amdgcn_readlane((unsigned int)(x >> 32), ln);
    return ((u64)hi << 32) | (u64)lo;
}

template <int NR>
__device__ __forceinline__ void load_chunk(u64* __restrict__ buf,
        const u64* __restrict__ S, int base, int lw) {
#pragma unroll
    for (int c = 0; c < NR; ++c)
        buf[c] = S[(size_t)(base + c) * 32 + lw];
}

template <int NR>
__device__ __forceinline__ void process_chunk(const u64* __restrict__ buf,
        int wi, u64& r0, u64& r1, u64& cur) {
    cur = ~readlane64(r0 | r1, wi);
#pragma unroll
    for (int g = 0; g < NR / 16; ++g) {
        const int b0 = g * 16;
        u64 t0 = (buf[b0+0] | buf[b0+1]) | (buf[b0+2] | buf[b0+3]);
        u64 t1 = (buf[b0+4] | buf[b0+5]) | (buf[b0+6] | buf[b0+7]);
        u64 t2 = (buf[b0+8] | buf[b0+9]) | (buf[b0+10] | buf[b0+11]);
        u64 t3 = (buf[b0+12] | buf[b0+13]) | (buf[b0+14] | buf[b0+15]);
        u64 tor = (t0 | t1) | (t2 | t3);
        u64 intra = readlane64(tor, wi);
        if (intra == 0ull) {
#pragma unroll
            for (int c = 0; c < 16; ++c) {
                u64 msk = ((cur >> (b0 + c)) & 1ull) ? ~0ull : 0ull;
                if (c & 1) r1 |= buf[b0+c] & msk; else r0 |= buf[b0+c] & msk;
            }
        } else {
#pragma unroll
            for (int c = 0; c < 16; ++c) {
                if ((cur >> (b0 + c)) & 1ull) {
                    cur &= ~readlane64(buf[b0+c], wi);
                    if (c & 1) r1 |= buf[b0+c]; else r0 |= buf[b0+c];
                }
            }
        }
    }
}

__global__ __launch_bounds__(64) void k_final(const u64* __restrict__ supp,
                        const float4* __restrict__ pre_boxes,
                        const float* __restrict__ pre_scores,
                        float* __restrict__ out) {
    const int b = blockIdx.x;
    const int lane = threadIdx.x;
    float* ob = out + (size_t)b * POST_K * 4;
    float* os = out + (size_t)BATCH * POST_K * 4 + (size_t)b * POST_K;
    for (int t = lane; t < POST_K * 4; t += 64) ob[t] = 0.0f;
    for (int t = lane; t < POST_K; t += 64) os[t] = 0.0f;

    const u64* S = supp + (size_t)b * PRE_K * 32;
    const int lw = lane & 31;
    u64 r0 = 0ull, r1 = 0ull, cur = ~0ull;
    u64 A[64], B[64];
    load_chunk<64>(A, S, 0, lw);
    for (int ch = 0; ch < 30; ch += 2) {
        load_chunk<64>(B, S, (ch + 1) * 64, lw);
        process_chunk<64>(A, ch, r0, r1, cur);
        load_chunk<64>(A, S, (ch + 2) * 64, lw);
        process_chunk<64>(B, ch + 1, r0, r1, cur);
    }
    load_chunk<16>(B, S, 31 * 64, lw);
    process_chunk<64>(A, 30, r0, r1, cur);
    process_chunk<16>(B, 31, r0, r1, cur);
    const u64 removed = r0 | r1;

    u64 kw = ~removed;
    if (lw == 31) kw &= 0xFFFFull;  // rows 1984..1999 only
    int cnt = (lane < 32) ? __builtin_popcountll(kw) : 0;
    int cum = cnt;
#pragma unroll
    for (int d = 1; d < 64; d <<= 1) {
        int v = __shfl_up(cum, d);
        if (lane >= d) cum += v;
    }
    int r = cum - cnt;
    __syncthreads();
    if (lane < 32) {
        u64 m = kw;
        while (m != 0ull && r < POST_K) {
            int t = __builtin_ctzll(m);
            m &= m - 1ull;
            int i = lw * 64 + t;
            float4 bx = pre_boxes[(size_t)b * PRE_K + i];
            ob[r * 4 + 0] = fminf(fmaxf(bx.x, 0.0f), 1.0f);
            ob[r * 4 + 1] = fminf(fmaxf(bx.y, 0.0f), 1.0f);
            ob[r * 4 + 2] = fminf(fmaxf(bx.z, 0.0f), 1.0f);
            ob[r * 4 + 3] = fminf(fmaxf(bx.w, 0.0f), 1.0f);
            os[r] = pre_scores[(size_t)b * PRE_K + i];
            ++r;
        }
    }
}

extern "C" void kernel_launch(void* const* d_in, const int* in_sizes, int n_in,
                              void* d_out, int out_size, void* d_ws, size_t ws_size,
                              hipStream_t stream) {
    const float* deltas  = (const float*)d_in[0];
    const float* labels  = (const float*)d_in[1];
    const float* anchors = (const float*)d_in[2];
    float* out = (float*)d_out;

    char* ws = (char*)d_ws;
    float* scores          = (float*)(ws + WS_SC);
    unsigned int* hist     = (unsigned int*)(ws + WS_A);
    u64* cd                = (u64*)(ws + WS_A);   // reuses hist
    u64* sp                = (u64*)(ws + WS_A);   // reuses cand
    unsigned int* cntp     = (unsigned int*)(ws + WS_CNT);
    unsigned int* cutp     = (unsigned int*)(ws + WS_CUT);
    float4* pre_boxes      = (float4*)(ws + WS_PB);              // reuses scores
    float* pre_scores      = (float*)(ws + WS_PS);

    k_zero<<<(BATCH * NBIN + 255) / 256, 256, 0, stream>>>(hist);
    k_softhist<<<(BATCH * FHh * FWw + 255) / 256, 256, 0, stream>>>(labels, scores, hist);
    k_cut<<<BATCH, 1024, 0, stream>>>(hist, cutp);
    k_gather<<<BATCH * SEGS, 256, 0, stream>>>(scores, cutp, cd, cntp);
    k_sortdec<<<BATCH, SORT_T, 0, stream>>>(cd, cntp, deltas, anchors, pre_boxes, pre_scores);
    k_iou<<<dim3(32, 32, BATCH), 64, 0, stream>>>(pre_boxes, sp);
    k_final<<<BATCH, 64, 0, stream>>>(sp, pre_boxes, pre_scores, out);
}

// Round 8
// 165.015 us; speedup vs baseline: 1.2209x; 1.0459x over previous
//
#include <hip/hip_runtime.h>
#include <cstdint>
#include <cstddef>

#define BATCH 8
#define FHh   32
#define FWw   256
#define NA    6
#define NANCH (FHh * FWw * NA)   // 49152
#define PRE_K 2000
#define POST_K 300
#define NBIN  65536
#define SEGS  192                // blocks per batch in k_gather (NANCH/256)
#define SKEYN 4096
#define SORT_T 256
#define ELEMS  16                // elements per thread in k_sortdec
// padded LDS index: +1 u64 per 16 -> per-thread stride 17 (odd) kills the
// 32-way bank conflict of the 128B-stride chunk layout (r6: 797K conflicts)
#define SK(i) ((i) + ((i) >> 4))
#define SKPAD (SKEYN + (SKEYN >> 4))   // 4352

typedef unsigned long long u64;

// ---------------- workspace layout (bytes), total 5,675,520 ----------------
#define WS_SC   0
#define WS_PB   0
#define WS_PS   256000
#define WS_A    1572864
#define WS_CNT  5668864
#define WS_CUT  5675008

// ---------------- K0: zero histogram ----------------
__global__ void k_zero(unsigned int* __restrict__ hist) {
    int g = blockIdx.x * blockDim.x + threadIdx.x;
    if (g < BATCH * NBIN) hist[g] = 0u;
}

// ---------------- K1: fused softmax + 16-bit-key histogram ----------------
__global__ void k_softhist(const float* __restrict__ labels, float* __restrict__ scores,
                           unsigned int* __restrict__ hist) {
    int pos = blockIdx.x * blockDim.x + threadIdx.x;  // over BATCH*FH*FW
    if (pos >= BATCH * FHh * FWw) return;
    int b = pos / (FHh * FWw);
    const float2* in2 = (const float2*)(labels + (size_t)pos * NA);
    float v[NA];
    float2 p0 = in2[0], p1 = in2[1], p2 = in2[2];
    v[0] = p0.x; v[1] = p0.y; v[2] = p1.x; v[3] = p1.y; v[4] = p2.x; v[5] = p2.y;
    float m = v[0];
#pragma unroll
    for (int a = 1; a < NA; ++a) m = fmaxf(m, v[a]);
    float s = 0.0f;
#pragma unroll
    for (int a = 0; a < NA; ++a) { v[a] = expf(v[a] - m); s += v[a]; }
    float inv = 1.0f / s;
    float2* o2 = (float2*)(scores + (size_t)pos * NA);
    unsigned int* hb = hist + (size_t)b * NBIN;
#pragma unroll
    for (int a = 0; a < NA; ++a) v[a] *= inv;
    o2[0] = make_float2(v[0], v[1]);
    o2[1] = make_float2(v[2], v[3]);
    o2[2] = make_float2(v[4], v[5]);
#pragma unroll
    for (int a = 0; a < NA; ++a)
        atomicAdd(&hb[__float_as_uint(v[a]) >> 16], 1u);  // fire-and-forget
}

// ---------------- K2: per-batch find 16-bit cutoff bin ----------------
__global__ __launch_bounds__(1024) void k_cut(const unsigned int* __restrict__ hist,
                                              unsigned int* __restrict__ cut) {
    const int b = blockIdx.x;
    const int tid = threadIdx.x;
    const unsigned int* h = hist + (size_t)b * NBIN;
    const int blk0 = NBIN - 64 * (tid + 1);
    const uint4* h4 = (const uint4*)(h + blk0);
    unsigned int s = 0;
#pragma unroll
    for (int k = 0; k < 16; ++k) {
        uint4 q = h4[k];
        s += q.x + q.y + q.z + q.w;
    }
    const int lane = tid & 63, wid = tid >> 6;
    unsigned int inc = s;
#pragma unroll
    for (int d = 1; d < 64; d <<= 1) {
        unsigned int v = __shfl_up(inc, d);
        if (lane >= d) inc += v;
    }
    __shared__ unsigned int wtot[16];
    if (lane == 63) wtot[wid] = inc;
    __syncthreads();
    unsigned int woff = 0;
    for (int w = 0; w < 16; ++w) if (w < wid) woff += wtot[w];
    unsigned int excl = woff + inc - s;  // count strictly above this block
    if (excl < PRE_K && excl + s >= PRE_K) {
        const int base = NBIN - 1 - tid * 64;  // top bin of the block
        unsigned int run = excl;
        for (int k = 0; k < 64; ++k) {
            run += h[base - k];
            if (run >= PRE_K) { cut[b * 16] = (unsigned int)(base - k); break; }
        }
    }
}

// ------- K3: atomic-free gather. block = (batch b, segment kb of 256 anchors) -
__global__ __launch_bounds__(256) void k_gather(
        const float* __restrict__ scores, const unsigned int* __restrict__ cut,
        u64* __restrict__ cand, unsigned int* __restrict__ counts) {
    const int blk = blockIdx.x;
    const int b = blk / SEGS, kb = blk - b * SEGS;
    const int tid = threadIdx.x;
    __shared__ unsigned int s_cut;
    __shared__ unsigned int s_wcnt[4];
    if (tid == 0) s_cut = cut[b * 16];
    __syncthreads();
    const int idx = kb * 256 + tid;                       // batch-local anchor
    const unsigned int bits = __float_as_uint(scores[(size_t)b * NANCH + idx]);
    const bool pass = (bits >> 16) >= s_cut;
    const u64 m = __ballot(pass);
    const int lane = tid & 63, w = tid >> 6;
    if (lane == 0) s_wcnt[w] = (unsigned int)__popcll(m);
    __syncthreads();
    unsigned int pre = 0, tot = 0;
#pragma unroll
    for (int i = 0; i < 4; ++i) { unsigned int c = s_wcnt[i]; if (i < w) pre += c; tot += c; }
    if (pass) {
        unsigned int rank = pre + (unsigned int)__popcll(m & ((1ull << lane) - 1ull));
        cand[((size_t)b * SEGS + kb) * 256 + rank] =
            ((u64)bits << 32) | (unsigned int)(~idx);
    }
    if (tid == 0) counts[b * SEGS + kb] = tot;
}

// ---- K4: register-resident bitonic sort of 4096 + decode top-2000 ----------
__global__ __launch_bounds__(SORT_T) void k_sortdec(
        const u64* __restrict__ cand, const unsigned int* __restrict__ counts,
        const float* __restrict__ deltas, const float* __restrict__ anchors,
        float4* __restrict__ pre_boxes, float* __restrict__ pre_scores) {
    const int b = blockIdx.x;
    const int tid = threadIdx.x;
    __shared__ u64 skey[SKPAD];
    __shared__ unsigned int s_wsum[4];
    for (int i = tid; i < SKPAD; i += SORT_T) skey[i] = 0ull;

    // scan the 192 per-segment counts (4 waves; only first 3 carry data)
    unsigned int v = (tid < SEGS) ? counts[b * SEGS + tid] : 0u;
    const int lane = tid & 63, wid = tid >> 6;
    unsigned int inc = v;
#pragma unroll
    for (int d = 1; d < 64; d <<= 1) {
        unsigned int t = __shfl_up(inc, d);
        if (lane >= d) inc += t;
    }
    if (lane == 63) s_wsum[wid] = inc;
    __syncthreads();
    if (tid < SEGS) {
        unsigned int woff = 0;
        for (int i = 0; i < wid; ++i) woff += s_wsum[i];
        unsigned int off = woff + inc - v;  // exclusive prefix
        const u64* seg = cand + ((size_t)b * SEGS + tid) * 256;
        for (unsigned int k = 0; k < v; ++k) {
            unsigned int p = off + k;
            if (p < SKEYN) skey[SK(p)] = seg[k];
        }
    }
    __syncthreads();

    // own chunk -> registers (stride-17 u64: conflict-free floor)
    u64 r[ELEMS];
    const int base = tid * ELEMS;
#pragma unroll
    for (int e = 0; e < ELEMS; ++e) r[e] = skey[SK(base + e)];

    // ---- in-register levels k = 2..16 (all j < 16) ----
#pragma unroll
    for (int k = 2; k <= ELEMS; k <<= 1) {
#pragma unroll
        for (int j = ELEMS; j >= 1; j >>= 1) {
            if (j >= k) continue;  // j runs k/2..1
#pragma unroll
            for (int e = 0; e < ELEMS; ++e) {
                int pe = e ^ j;
                if (pe > e) {
                    bool desc = (((base + e) & k) == 0);
                    u64 a = r[e], c = r[pe];
                    if ((a < c) == desc) { r[e] = c; r[pe] = a; }
                }
            }
        }
    }

    // ---- levels k = 32..4096: cross-thread j>=16 via LDS, then j<16 in-reg --
    for (int k = 2 * ELEMS; k <= SKEYN; k <<= 1) {
        const bool desc = ((base & k) == 0);  // uniform per thread (k >= 32)
        for (int j = k >> 1; j >= ELEMS; j >>= 1) {
            __syncthreads();  // previous reads done before overwrite
#pragma unroll
            for (int e = 0; e < ELEMS; ++e) skey[SK(base + e)] = r[e];
            __syncthreads();
            const int pt = tid ^ (j / ELEMS);
            const bool low = (tid & (j / ELEMS)) == 0;
            const bool takeMax = (low == desc);
            const int pbase = pt * ELEMS;
#pragma unroll
            for (int e = 0; e < ELEMS; ++e) {
                u64 o = skey[SK(pbase + e)];
                u64 a = r[e];
                r[e] = takeMax ? (a > o ? a : o) : (a < o ? a : o);
            }
        }
#pragma unroll
        for (int j = ELEMS / 2; j >= 1; j >>= 1) {
#pragma unroll
            for (int e = 0; e < ELEMS; ++e) {
                int pe = e ^ j;
                if (pe > e) {
                    u64 a = r[e], c = r[pe];
                    if ((a < c) == desc) { r[e] = c; r[pe] = a; }
                }
            }
        }
    }

    // write back sorted keys, then decode top-2000 strided
    __syncthreads();
#pragma unroll
    for (int e = 0; e < ELEMS; ++e) skey[SK(base + e)] = r[e];
    __syncthreads();

    for (int t = tid; t < PRE_K; t += SORT_T) {
        u64 key = skey[SK(t)];
        int idx = (int)(~(unsigned int)key);
        float score = __uint_as_float((unsigned int)(key >> 32));
        const float* anc = anchors + (size_t)idx * 4;
        const float* del = deltas + ((size_t)b * NANCH + idx) * 4;
        float a0 = anc[0], a1 = anc[1], a2 = anc[2], a3 = anc[3];
        float ah = a2 - a0, aw = a3 - a1;
        float acy = a0 + 0.5f * ah, acx = a1 + 0.5f * aw;
        float d0 = del[0] * 0.1f, d1 = del[1] * 0.1f;
        float d2 = del[2] * 0.2f, d3 = del[3] * 0.2f;
        float bh = expf(d2) * ah, bw = expf(d3) * aw;
        float bcy = d0 * ah + acy, bcx = d1 * aw + acx;
        float y1 = bcy - 0.5f * bh, x1 = bcx - 0.5f * bw;
        pre_boxes[(size_t)b * PRE_K + t] = make_float4(y1, x1, y1 + bh, x1 + bw);
        pre_scores[(size_t)b * PRE_K + t] = score;
    }
}

// ---------------- K5: suppression bit-matrix (LDS-staged cols) ----------------
__global__ __launch_bounds__(64) void k_iou(const float4* __restrict__ pre_boxes,
                                            u64* __restrict__ supp) {
    const int cb = blockIdx.x;   // col word 0..31
    const int rb = blockIdx.y;   // row block 0..31
    const int b  = blockIdx.z;
    const int lane = threadIdx.x;
    const int i = rb * 64 + lane;
    const int j0 = cb * 64;
    if (cb < rb) {
        if (i < PRE_K) supp[((size_t)b * PRE_K + i) * 32 + cb] = 0ull;
        return;
    }
    __shared__ float4 sbox[64];
    const float4* boxes = pre_boxes + (size_t)b * PRE_K;
    int j = j0 + lane;
    sbox[lane] = (j < PRE_K) ? boxes[j] : make_float4(0.f, 0.f, 0.f, 0.f);
    __syncthreads();
    if (i >= PRE_K) return;
    float4 bi = boxes[i];
    float area_i = (bi.z - bi.x) * (bi.w - bi.y);
    u64 bits = 0ull;
    const int tmax = (PRE_K - j0 < 64) ? (PRE_K - j0) : 64;
    for (int t = 0; t < tmax; ++t) {
        int jj = j0 + t;
        if (jj <= i) continue;
        float4 bj = sbox[t];
        float iy1 = fmaxf(bi.x, bj.x), ix1 = fmaxf(bi.y, bj.y);
        float iy2 = fminf(bi.z, bj.z), ix2 = fminf(bi.w, bj.w);
        float inter = fmaxf(iy2 - iy1, 0.0f) * fmaxf(ix2 - ix1, 0.0f);
        float area_j = (bj.z - bj.x) * (bj.w - bj.y);
        float uni = area_i + area_j - inter;
        float iou = inter / fmaxf(uni, 1e-8f);
        if (iou > 0.7f) bits |= (1ull << t);
    }
    supp[((size_t)b * PRE_K + i) * 32 + cb] = bits;
}

// ---------------- K6: serial greedy reduce + compact + outputs ----------------
// Async LDS double-buffer via global_load_lds (no VGPR staging, counted vmcnt).
// Lanes 0-31: even rows, word l&31; lanes 32-63: odd rows. Epoch = 64 rows =
// one keep-word; cur (wave-uniform SGPR) refreshed per epoch.
__device__ __forceinline__ u64 readlane64(u64 x, int ln) {
    unsigned int lo = __builtin_amdgcn_readlane((unsigned int)x, ln);
    unsigned int hi = __builtin_amdgcn_readlane((unsigned int)(x >> 32), ln);
    return ((u64)hi << 32) | (u64)lo;
}

template <int ROWS>
__device__ __forceinline__ void proc_epoch(const u64* __restrict__ bufp, int wi,
                                           int p, int w, u64& r0, u64& r1) {
    u64 acc = r0 | r1;
    u64 cur = ~(readlane64(acc, wi) | readlane64(acc, 32 + wi));
#pragma unroll
    for (int g = 0; g < ROWS / 16; ++g) {
        u64 ld[8];
#pragma unroll
        for (int k = 0; k < 8; ++k)
            ld[k] = bufp[(g * 16 + 2 * k + p) * 32 + w];
        u64 t0 = (ld[0] | ld[1]) | (ld[2] | ld[3]);
        u64 t1 = (ld[4] | ld[5]) | (ld[6] | ld[7]);
        u64 tor = t0 | t1;
        u64 intra = readlane64(tor, wi) | readlane64(tor, 32 + wi);
        if (intra == 0ull) {
            // no row of this subgroup suppresses anything in word wi ->
            // cur invariant across subgroup -> branchless masked ORs
#pragma unroll
            for (int k = 0; k < 8; ++k) {
                int bitpos = g * 16 + 2 * k + p;   // per-lane (parity)
                u64 msk = ((cur >> bitpos) & 1ull) ? ~0ull : 0ull;
                if (k & 1) r1 |= ld[k] & msk; else r0 |= ld[k] & msk;
            }
        } else {
            // exact per-row walk (wave-uniform branches)
#pragma unroll
            for (int c = 0; c < 16; ++c) {
                const int pi = c & 1, k = c >> 1;
                if ((cur >> (g * 16 + c)) & 1ull) {
                    cur &= ~readlane64(ld[k], pi * 32 + wi);
                    u64 msk = (p == pi) ? ~0ull : 0ull;
                    if (k & 1) r1 |= ld[k] & msk; else r0 |= ld[k] & msk;
                }
            }
        }
    }
}

__global__ __launch_bounds__(64) void k_final(const u64* __restrict__ supp,
                        const float4* __restrict__ pre_boxes,
                        const float* __restrict__ pre_scores,
                        float* __restrict__ out) {
    const int b = blockIdx.x;
    const int l = threadIdx.x;
    const int p = l >> 5, w = l & 31;
    float* ob = out + (size_t)b * POST_K * 4;
    float* os = out + (size_t)BATCH * POST_K * 4 + (size_t)b * POST_K;
    for (int t = l; t < POST_K * 4; t += 64) ob[t] = 0.0f;
    for (int t = l; t < POST_K; t += 64) os[t] = 0.0f;
    // drain stores so counted vmcnt below only sees staging loads
    asm volatile("s_waitcnt vmcnt(0)" ::: "memory");

    __shared__ u64 sbuf[2][2048];   // 2 x 16KB epoch buffers
    const char* Sb = (const char*)(supp + (size_t)b * PRE_K * 32);

#define ISSUE_EPOCH(ep, nchunks)                                              \
    do {                                                                      \
        const char* gsrc_ = Sb + (size_t)(ep) * 16384 + (size_t)l * 16;       \
        char* ldst_ = (char*)&sbuf[(ep) & 1][0];                              \
        _Pragma("unroll")                                                     \
        for (int k_ = 0; k_ < (nchunks); ++k_)                                \
            __builtin_amdgcn_global_load_lds(                                 \
                (const __attribute__((address_space(1))) void*)(gsrc_ + k_ * 1024), \
                (__attribute__((address_space(3))) void*)(ldst_ + k_ * 1024), \
                16, 0, 0);                                                    \
    } while (0)

    u64 r0 = 0ull, r1 = 0ull;
    ISSUE_EPOCH(0, 16);
    for (int e = 0; e < 30; ++e) {
        ISSUE_EPOCH(e + 1, 16);
        asm volatile("s_waitcnt vmcnt(16)" ::: "memory");  // epoch e landed
        __builtin_amdgcn_sched_barrier(0);
        proc_epoch<64>(&sbuf[e & 1][0], e, p, w, r0, r1);
    }
    ISSUE_EPOCH(31, 4);                                     // tail: 16 rows
    asm volatile("s_waitcnt vmcnt(4)" ::: "memory");        // epoch 30 landed
    __builtin_amdgcn_sched_barrier(0);
    proc_epoch<64>(&sbuf[0][0], 30, p, w, r0, r1);
    asm volatile("s_waitcnt vmcnt(0)" ::: "memory");        // tail landed
    __builtin_amdgcn_sched_barrier(0);
    proc_epoch<16>(&sbuf[1][0], 31, p, w, r0, r1);
#undef ISSUE_EPOCH

    // merge parity halves: removed word w = lane(w) | lane(w+32)
    u64 full = r0 | r1;
    u64 oth = __shfl(full, w + 32);
    u64 kw = ~(full | oth);
    if (w == 31) kw &= 0xFFFFull;  // rows 1984..1999 only
    int cnt = (l < 32) ? __builtin_popcountll(kw) : 0;
    int cum = cnt;
#pragma unroll
    for (int d = 1; d < 64; d <<= 1) {
        int v = __shfl_up(cum, d);
        if (l >= d) cum += v;
    }
    int r = cum - cnt;
    __syncthreads();
    if (l < 32) {
        u64 m = kw;
        while (m != 0ull && r < POST_K) {
            int t = __builtin_ctzll(m);
            m &= m - 1ull;
            int i = w * 64 + t;
            float4 bx = pre_boxes[(size_t)b * PRE_K + i];
            ob[r * 4 + 0] = fminf(fmaxf(bx.x, 0.0f), 1.0f);
            ob[r * 4 + 1] = fminf(fmaxf(bx.y, 0.0f), 1.0f);
            ob[r * 4 + 2] = fminf(fmaxf(bx.z, 0.0f), 1.0f);
            ob[r * 4 + 3] = fminf(fmaxf(bx.w, 0.0f), 1.0f);
            os[r] = pre_scores[(size_t)b * PRE_K + i];
            ++r;
        }
    }
}

extern "C" void kernel_launch(void* const* d_in, const int* in_sizes, int n_in,
                              void* d_out, int out_size, void* d_ws, size_t ws_size,
                              hipStream_t stream) {
    const float* deltas  = (const float*)d_in[0];
    const float* labels  = (const float*)d_in[1];
    const float* anchors = (const float*)d_in[2];
    float* out = (float*)d_out;

    char* ws = (char*)d_ws;
    float* scores          = (float*)(ws + WS_SC);
    unsigned int* hist     = (unsigned int*)(ws + WS_A);
    u64* cd                = (u64*)(ws + WS_A);   // reuses hist
    u64* sp                = (u64*)(ws + WS_A);   // reuses cand
    unsigned int* cntp     = (unsigned int*)(ws + WS_CNT);
    unsigned int* cutp     = (unsigned int*)(ws + WS_CUT);
    float4* pre_boxes      = (float4*)(ws + WS_PB);              // reuses scores
    float* pre_scores      = (float*)(ws + WS_PS);

    k_zero<<<(BATCH * NBIN + 255) / 256, 256, 0, stream>>>(hist);
    k_softhist<<<(BATCH * FHh * FWw + 255) / 256, 256, 0, stream>>>(labels, scores, hist);
    k_cut<<<BATCH, 1024, 0, stream>>>(hist, cutp);
    k_gather<<<BATCH * SEGS, 256, 0, stream>>>(scores, cutp, cd, cntp);
    k_sortdec<<<BATCH, SORT_T, 0, stream>>>(cd, cntp, deltas, anchors, pre_boxes, pre_scores);
    k_iou<<<dim3(32, 32, BATCH), 64, 0, stream>>>(pre_boxes, sp);
    k_final<<<BATCH, 64, 0, stream>>>(sp, pre_boxes, pre_scores, out);
}

// Round 9
// 138.426 us; speedup vs baseline: 1.4554x; 1.1921x over previous
//
#include <hip/hip_runtime.h>
#include <cstdint>
#include <cstddef>

#define BATCH 8
#define FHh   32
#define FWw   256
#define NA    6
#define NANCH (FHh * FWw * NA)   // 49152
#define PRE_K 2000
#define POST_K 300
#define NBIN  65536
#define SEGS  192                // blocks per batch in k_gather (NANCH/256)
#define SKEYN 4096
#define SORT_T 256
#define ELEMS  16                // elements per thread in k_sortdec
// padded LDS index: +1 u64 per 16 -> per-thread stride 17 (odd) kills the
// 32-way bank conflict of the 128B-stride chunk layout (r6: 797K conflicts)
#define SK(i) ((i) + ((i) >> 4))
#define SKPAD (SKEYN + (SKEYN >> 4))   // 4352

typedef unsigned long long u64;

// ---------------- workspace layout (bytes), total 5,675,520 ----------------
#define WS_SC   0
#define WS_PB   0
#define WS_PS   256000
#define WS_A    1572864
#define WS_CNT  5668864
#define WS_CUT  5675008

// ---------------- K0: zero histogram ----------------
__global__ void k_zero(unsigned int* __restrict__ hist) {
    int g = blockIdx.x * blockDim.x + threadIdx.x;
    if (g < BATCH * NBIN) hist[g] = 0u;
}

// ---------------- K1: fused softmax + 16-bit-key histogram ----------------
__global__ void k_softhist(const float* __restrict__ labels, float* __restrict__ scores,
                           unsigned int* __restrict__ hist) {
    int pos = blockIdx.x * blockDim.x + threadIdx.x;  // over BATCH*FH*FW
    if (pos >= BATCH * FHh * FWw) return;
    int b = pos / (FHh * FWw);
    const float2* in2 = (const float2*)(labels + (size_t)pos * NA);
    float v[NA];
    float2 p0 = in2[0], p1 = in2[1], p2 = in2[2];
    v[0] = p0.x; v[1] = p0.y; v[2] = p1.x; v[3] = p1.y; v[4] = p2.x; v[5] = p2.y;
    float m = v[0];
#pragma unroll
    for (int a = 1; a < NA; ++a) m = fmaxf(m, v[a]);
    float s = 0.0f;
#pragma unroll
    for (int a = 0; a < NA; ++a) { v[a] = expf(v[a] - m); s += v[a]; }
    float inv = 1.0f / s;
    float2* o2 = (float2*)(scores + (size_t)pos * NA);
    unsigned int* hb = hist + (size_t)b * NBIN;
#pragma unroll
    for (int a = 0; a < NA; ++a) v[a] *= inv;
    o2[0] = make_float2(v[0], v[1]);
    o2[1] = make_float2(v[2], v[3]);
    o2[2] = make_float2(v[4], v[5]);
#pragma unroll
    for (int a = 0; a < NA; ++a)
        atomicAdd(&hb[__float_as_uint(v[a]) >> 16], 1u);  // fire-and-forget
}

// ---------------- K2: per-batch find 16-bit cutoff bin ----------------
__global__ __launch_bounds__(1024) void k_cut(const unsigned int* __restrict__ hist,
                                              unsigned int* __restrict__ cut) {
    const int b = blockIdx.x;
    const int tid = threadIdx.x;
    const unsigned int* h = hist + (size_t)b * NBIN;
    const int blk0 = NBIN - 64 * (tid + 1);
    const uint4* h4 = (const uint4*)(h + blk0);
    unsigned int s = 0;
#pragma unroll
    for (int k = 0; k < 16; ++k) {
        uint4 q = h4[k];
        s += q.x + q.y + q.z + q.w;
    }
    const int lane = tid & 63, wid = tid >> 6;
    unsigned int inc = s;
#pragma unroll
    for (int d = 1; d < 64; d <<= 1) {
        unsigned int v = __shfl_up(inc, d);
        if (lane >= d) inc += v;
    }
    __shared__ unsigned int wtot[16];
    if (lane == 63) wtot[wid] = inc;
    __syncthreads();
    unsigned int woff = 0;
    for (int w = 0; w < 16; ++w) if (w < wid) woff += wtot[w];
    unsigned int excl = woff + inc - s;  // count strictly above this block
    if (excl < PRE_K && excl + s >= PRE_K) {
        const int base = NBIN - 1 - tid * 64;  // top bin of the block
        unsigned int run = excl;
        for (int k = 0; k < 64; ++k) {
            run += h[base - k];
            if (run >= PRE_K) { cut[b * 16] = (unsigned int)(base - k); break; }
        }
    }
}

// ------- K3: atomic-free gather. block = (batch b, segment kb of 256 anchors) -
__global__ __launch_bounds__(256) void k_gather(
        const float* __restrict__ scores, const unsigned int* __restrict__ cut,
        u64* __restrict__ cand, unsigned int* __restrict__ counts) {
    const int blk = blockIdx.x;
    const int b = blk / SEGS, kb = blk - b * SEGS;
    const int tid = threadIdx.x;
    __shared__ unsigned int s_cut;
    __shared__ unsigned int s_wcnt[4];
    if (tid == 0) s_cut = cut[b * 16];
    __syncthreads();
    const int idx = kb * 256 + tid;                       // batch-local anchor
    const unsigned int bits = __float_as_uint(scores[(size_t)b * NANCH + idx]);
    const bool pass = (bits >> 16) >= s_cut;
    const u64 m = __ballot(pass);
    const int lane = tid & 63, w = tid >> 6;
    if (lane == 0) s_wcnt[w] = (unsigned int)__popcll(m);
    __syncthreads();
    unsigned int pre = 0, tot = 0;
#pragma unroll
    for (int i = 0; i < 4; ++i) { unsigned int c = s_wcnt[i]; if (i < w) pre += c; tot += c; }
    if (pass) {
        unsigned int rank = pre + (unsigned int)__popcll(m & ((1ull << lane) - 1ull));
        cand[((size_t)b * SEGS + kb) * 256 + rank] =
            ((u64)bits << 32) | (unsigned int)(~idx);
    }
    if (tid == 0) counts[b * SEGS + kb] = tot;
}

// ---- K4: register-resident bitonic sort of 4096 + decode top-2000 ----------
__global__ __launch_bounds__(SORT_T) void k_sortdec(
        const u64* __restrict__ cand, const unsigned int* __restrict__ counts,
        const float* __restrict__ deltas, const float* __restrict__ anchors,
        float4* __restrict__ pre_boxes, float* __restrict__ pre_scores) {
    const int b = blockIdx.x;
    const int tid = threadIdx.x;
    __shared__ u64 skey[SKPAD];
    __shared__ unsigned int s_wsum[4];
    for (int i = tid; i < SKPAD; i += SORT_T) skey[i] = 0ull;

    // scan the 192 per-segment counts (4 waves; only first 3 carry data)
    unsigned int v = (tid < SEGS) ? counts[b * SEGS + tid] : 0u;
    const int lane = tid & 63, wid = tid >> 6;
    unsigned int inc = v;
#pragma unroll
    for (int d = 1; d < 64; d <<= 1) {
        unsigned int t = __shfl_up(inc, d);
        if (lane >= d) inc += t;
    }
    if (lane == 63) s_wsum[wid] = inc;
    __syncthreads();
    if (tid < SEGS) {
        unsigned int woff = 0;
        for (int i = 0; i < wid; ++i) woff += s_wsum[i];
        unsigned int off = woff + inc - v;  // exclusive prefix
        const u64* seg = cand + ((size_t)b * SEGS + tid) * 256;
        for (unsigned int k = 0; k < v; ++k) {
            unsigned int p = off + k;
            if (p < SKEYN) skey[SK(p)] = seg[k];
        }
    }
    __syncthreads();

    // own chunk -> registers (stride-17 u64: conflict-free floor)
    u64 r[ELEMS];
    const int base = tid * ELEMS;
#pragma unroll
    for (int e = 0; e < ELEMS; ++e) r[e] = skey[SK(base + e)];

    // ---- in-register levels k = 2..16 (all j < 16) ----
#pragma unroll
    for (int k = 2; k <= ELEMS; k <<= 1) {
#pragma unroll
        for (int j = ELEMS; j >= 1; j >>= 1) {
            if (j >= k) continue;  // j runs k/2..1
#pragma unroll
            for (int e = 0; e < ELEMS; ++e) {
                int pe = e ^ j;
                if (pe > e) {
                    bool desc = (((base + e) & k) == 0);
                    u64 a = r[e], c = r[pe];
                    if ((a < c) == desc) { r[e] = c; r[pe] = a; }
                }
            }
        }
    }

    // ---- levels k = 32..4096: cross-thread j>=16 via LDS, then j<16 in-reg --
    for (int k = 2 * ELEMS; k <= SKEYN; k <<= 1) {
        const bool desc = ((base & k) == 0);  // uniform per thread (k >= 32)
        for (int j = k >> 1; j >= ELEMS; j >>= 1) {
            __syncthreads();  // previous reads done before overwrite
#pragma unroll
            for (int e = 0; e < ELEMS; ++e) skey[SK(base + e)] = r[e];
            __syncthreads();
            const int pt = tid ^ (j / ELEMS);
            const bool low = (tid & (j / ELEMS)) == 0;
            const bool takeMax = (low == desc);
            const int pbase = pt * ELEMS;
#pragma unroll
            for (int e = 0; e < ELEMS; ++e) {
                u64 o = skey[SK(pbase + e)];
                u64 a = r[e];
                r[e] = takeMax ? (a > o ? a : o) : (a < o ? a : o);
            }
        }
#pragma unroll
        for (int j = ELEMS / 2; j >= 1; j >>= 1) {
#pragma unroll
            for (int e = 0; e < ELEMS; ++e) {
                int pe = e ^ j;
                if (pe > e) {
                    u64 a = r[e], c = r[pe];
                    if ((a < c) == desc) { r[e] = c; r[pe] = a; }
                }
            }
        }
    }

    // write back sorted keys, then decode top-2000 strided
    __syncthreads();
#pragma unroll
    for (int e = 0; e < ELEMS; ++e) skey[SK(base + e)] = r[e];
    __syncthreads();

    for (int t = tid; t < PRE_K; t += SORT_T) {
        u64 key = skey[SK(t)];
        int idx = (int)(~(unsigned int)key);
        float score = __uint_as_float((unsigned int)(key >> 32));
        const float* anc = anchors + (size_t)idx * 4;
        const float* del = deltas + ((size_t)b * NANCH + idx) * 4;
        float a0 = anc[0], a1 = anc[1], a2 = anc[2], a3 = anc[3];
        float ah = a2 - a0, aw = a3 - a1;
        float acy = a0 + 0.5f * ah, acx = a1 + 0.5f * aw;
        float d0 = del[0] * 0.1f, d1 = del[1] * 0.1f;
        float d2 = del[2] * 0.2f, d3 = del[3] * 0.2f;
        float bh = expf(d2) * ah, bw = expf(d3) * aw;
        float bcy = d0 * ah + acy, bcx = d1 * aw + acx;
        float y1 = bcy - 0.5f * bh, x1 = bcx - 0.5f * bw;
        pre_boxes[(size_t)b * PRE_K + t] = make_float4(y1, x1, y1 + bh, x1 + bw);
        pre_scores[(size_t)b * PRE_K + t] = score;
    }
}

// ---------------- K5: suppression bit-matrix (LDS-staged cols) ----------------
__global__ __launch_bounds__(64) void k_iou(const float4* __restrict__ pre_boxes,
                                            u64* __restrict__ supp) {
    const int cb = blockIdx.x;   // col word 0..31
    const int rb = blockIdx.y;   // row block 0..31
    const int b  = blockIdx.z;
    const int lane = threadIdx.x;
    const int i = rb * 64 + lane;
    const int j0 = cb * 64;
    if (cb < rb) {
        if (i < PRE_K) supp[((size_t)b * PRE_K + i) * 32 + cb] = 0ull;
        return;
    }
    __shared__ float4 sbox[64];
    const float4* boxes = pre_boxes + (size_t)b * PRE_K;
    int j = j0 + lane;
    sbox[lane] = (j < PRE_K) ? boxes[j] : make_float4(0.f, 0.f, 0.f, 0.f);
    __syncthreads();
    if (i >= PRE_K) return;
    float4 bi = boxes[i];
    float area_i = (bi.z - bi.x) * (bi.w - bi.y);
    u64 bits = 0ull;
    const int tmax = (PRE_K - j0 < 64) ? (PRE_K - j0) : 64;
    for (int t = 0; t < tmax; ++t) {
        int jj = j0 + t;
        if (jj <= i) continue;
        float4 bj = sbox[t];
        float iy1 = fmaxf(bi.x, bj.x), ix1 = fmaxf(bi.y, bj.y);
        float iy2 = fminf(bi.z, bj.z), ix2 = fminf(bi.w, bj.w);
        float inter = fmaxf(iy2 - iy1, 0.0f) * fmaxf(ix2 - ix1, 0.0f);
        float area_j = (bj.z - bj.x) * (bj.w - bj.y);
        float uni = area_i + area_j - inter;
        float iou = inter / fmaxf(uni, 1e-8f);
        if (iou > 0.7f) bits |= (1ull << t);
    }
    supp[((size_t)b * PRE_K + i) * 32 + cb] = bits;
}

// ---------------- K6: serial greedy reduce + compact + outputs ----------------
// Async LDS double-buffer via global_load_lds + counted vmcnt. Exact early
// exit: once >=POST_K rows are kept, later rows cannot affect the output.
__device__ __forceinline__ u64 readlane64(u64 x, int ln) {
    unsigned int lo = __builtin_amdgcn_readlane((unsigned int)x, ln);
    unsigned int hi = __builtin_amdgcn_readlane((unsigned int)(x >> 32), ln);
    return ((u64)hi << 32) | (u64)lo;
}

// returns the final keep mask (cur) of word wi — wave-uniform, exact
template <int ROWS>
__device__ __forceinline__ u64 proc_epoch(const u64* __restrict__ bufp, int wi,
                                          int p, int w, u64& r0, u64& r1) {
    u64 acc = r0 | r1;
    u64 cur = ~(readlane64(acc, wi) | readlane64(acc, 32 + wi));
#pragma unroll
    for (int g = 0; g < ROWS / 16; ++g) {
        u64 ld[8];
#pragma unroll
        for (int k = 0; k < 8; ++k)
            ld[k] = bufp[(g * 16 + 2 * k + p) * 32 + w];
        u64 t0 = (ld[0] | ld[1]) | (ld[2] | ld[3]);
        u64 t1 = (ld[4] | ld[5]) | (ld[6] | ld[7]);
        u64 tor = t0 | t1;
        u64 intra = readlane64(tor, wi) | readlane64(tor, 32 + wi);
        if (intra == 0ull) {
            // no row of this subgroup suppresses anything in word wi ->
            // cur invariant across subgroup -> branchless masked ORs
#pragma unroll
            for (int k = 0; k < 8; ++k) {
                int bitpos = g * 16 + 2 * k + p;   // per-lane (parity)
                u64 msk = ((cur >> bitpos) & 1ull) ? ~0ull : 0ull;
                if (k & 1) r1 |= ld[k] & msk; else r0 |= ld[k] & msk;
            }
        } else {
            // exact per-row walk (wave-uniform branches)
#pragma unroll
            for (int c = 0; c < 16; ++c) {
                const int pi = c & 1, k = c >> 1;
                if ((cur >> (g * 16 + c)) & 1ull) {
                    cur &= ~readlane64(ld[k], pi * 32 + wi);
                    u64 msk = (p == pi) ? ~0ull : 0ull;
                    if (k & 1) r1 |= ld[k] & msk; else r0 |= ld[k] & msk;
                }
            }
        }
    }
    return cur;
}

__global__ __launch_bounds__(64) void k_final(const u64* __restrict__ supp,
                        const float4* __restrict__ pre_boxes,
                        const float* __restrict__ pre_scores,
                        float* __restrict__ out) {
    const int b = blockIdx.x;
    const int l = threadIdx.x;
    const int p = l >> 5, w = l & 31;
    float* ob = out + (size_t)b * POST_K * 4;
    float* os = out + (size_t)BATCH * POST_K * 4 + (size_t)b * POST_K;
    for (int t = l; t < POST_K * 4; t += 64) ob[t] = 0.0f;
    for (int t = l; t < POST_K; t += 64) os[t] = 0.0f;
    // drain stores so counted vmcnt below only sees staging loads
    asm volatile("s_waitcnt vmcnt(0)" ::: "memory");

    __shared__ u64 sbuf[2][2048];   // 2 x 16KB epoch buffers
    const char* Sb = (const char*)(supp + (size_t)b * PRE_K * 32);

#define ISSUE_EPOCH(ep, nchunks)                                              \
    do {                                                                      \
        const char* gsrc_ = Sb + (size_t)(ep) * 16384 + (size_t)l * 16;       \
        char* ldst_ = (char*)&sbuf[(ep) & 1][0];                              \
        _Pragma("unroll")                                                     \
        for (int k_ = 0; k_ < (nchunks); ++k_)                                \
            __builtin_amdgcn_global_load_lds(                                 \
                (const __attribute__((address_space(1))) void*)(gsrc_ + k_ * 1024), \
                (__attribute__((address_space(3))) void*)(ldst_ + k_ * 1024), \
                16, 0, 0);                                                    \
    } while (0)

    u64 r0 = 0ull, r1 = 0ull;
    int kept = 0;
    ISSUE_EPOCH(0, 16);
    for (int e = 0; e < 32; ++e) {
        if (e < 30) {
            ISSUE_EPOCH(e + 1, 16);
            asm volatile("s_waitcnt vmcnt(16)" ::: "memory");  // epoch e landed
        } else if (e == 30) {
            ISSUE_EPOCH(31, 4);                                // tail: 16 rows
            asm volatile("s_waitcnt vmcnt(4)" ::: "memory");   // epoch 30 landed
        } else {
            asm volatile("s_waitcnt vmcnt(0)" ::: "memory");   // tail landed
        }
        __builtin_amdgcn_sched_barrier(0);
        u64 curf;
        if (e < 31) curf = proc_epoch<64>(&sbuf[e & 1][0], e, p, w, r0, r1);
        else        curf = proc_epoch<16>(&sbuf[e & 1][0], e, p, w, r0, r1) & 0xFFFFull;
        kept += __builtin_popcountll(curf);   // wave-uniform
        if (kept >= POST_K) break;            // exact: later rows can't matter
    }
    asm volatile("s_waitcnt vmcnt(0)" ::: "memory");  // drain in-flight prefetch
#undef ISSUE_EPOCH

    // merge parity halves: removed word w = lane(w) | lane(w+32)
    u64 full = r0 | r1;
    u64 oth = __shfl(full, w + 32);
    u64 kw = ~(full | oth);
    if (w == 31) kw &= 0xFFFFull;  // rows 1984..1999 only
    int cnt = (l < 32) ? __builtin_popcountll(kw) : 0;
    int cum = cnt;
#pragma unroll
    for (int d = 1; d < 64; d <<= 1) {
        int v = __shfl_up(cum, d);
        if (l >= d) cum += v;
    }
    int r = cum - cnt;
    __syncthreads();
    if (l < 32) {
        u64 m = kw;
        while (m != 0ull && r < POST_K) {
            int t = __builtin_ctzll(m);
            m &= m - 1ull;
            int i = w * 64 + t;
            float4 bx = pre_boxes[(size_t)b * PRE_K + i];
            ob[r * 4 + 0] = fminf(fmaxf(bx.x, 0.0f), 1.0f);
            ob[r * 4 + 1] = fminf(fmaxf(bx.y, 0.0f), 1.0f);
            ob[r * 4 + 2] = fminf(fmaxf(bx.z, 0.0f), 1.0f);
            ob[r * 4 + 3] = fminf(fmaxf(bx.w, 0.0f), 1.0f);
            os[r] = pre_scores[(size_t)b * PRE_K + i];
            ++r;
        }
    }
}

extern "C" void kernel_launch(void* const* d_in, const int* in_sizes, int n_in,
                              void* d_out, int out_size, void* d_ws, size_t ws_size,
                              hipStream_t stream) {
    const float* deltas  = (const float*)d_in[0];
    const float* labels  = (const float*)d_in[1];
    const float* anchors = (const float*)d_in[2];
    float* out = (float*)d_out;

    char* ws = (char*)d_ws;
    float* scores          = (float*)(ws + WS_SC);
    unsigned int* hist     = (unsigned int*)(ws + WS_A);
    u64* cd                = (u64*)(ws + WS_A);   // reuses hist
    u64* sp                = (u64*)(ws + WS_A);   // reuses cand
    unsigned int* cntp     = (unsigned int*)(ws + WS_CNT);
    unsigned int* cutp     = (unsigned int*)(ws + WS_CUT);
    float4* pre_boxes      = (float4*)(ws + WS_PB);              // reuses scores
    float* pre_scores      = (float*)(ws + WS_PS);

    k_zero<<<(BATCH * NBIN + 255) / 256, 256, 0, stream>>>(hist);
    k_softhist<<<(BATCH * FHh * FWw + 255) / 256, 256, 0, stream>>>(labels, scores, hist);
    k_cut<<<BATCH, 1024, 0, stream>>>(hist, cutp);
    k_gather<<<BATCH * SEGS, 256, 0, stream>>>(scores, cutp, cd, cntp);
    k_sortdec<<<BATCH, SORT_T, 0, stream>>>(cd, cntp, deltas, anchors, pre_boxes, pre_scores);
    k_iou<<<dim3(32, 32, BATCH), 64, 0, stream>>>(pre_boxes, sp);
    k_final<<<BATCH, 64, 0, stream>>>(sp, pre_boxes, pre_scores, out);
}

// Round 10
// 133.878 us; speedup vs baseline: 1.5049x; 1.0340x over previous
//
#include <hip/hip_runtime.h>
#include <cstdint>
#include <cstddef>

#define BATCH 8
#define FHh   32
#define FWw   256
#define NA    6
#define NANCH (FHh * FWw * NA)   // 49152
#define PRE_K 2000
#define POST_K 300
#define NBIN  65536
#define SEGS  192                // blocks per batch in k_gather (NANCH/256)
#define CAND_CAP 4096
#define NSLICE 16                // k_rank: candidate slices per batch

typedef unsigned long long u64;

// ---------------- workspace layout (bytes), total 5,675,520 ----------------
#define WS_SC   0
#define WS_PB   0
#define WS_PS   256000
#define WS_A    1572864
#define WS_CNT  5668864
#define WS_CUT  5675008

// ---------------- K0: zero histogram ----------------
__global__ void k_zero(unsigned int* __restrict__ hist) {
    int g = blockIdx.x * blockDim.x + threadIdx.x;
    if (g < BATCH * NBIN) hist[g] = 0u;
}

// ---------------- K1: fused softmax + 16-bit-key histogram ----------------
__global__ void k_softhist(const float* __restrict__ labels, float* __restrict__ scores,
                           unsigned int* __restrict__ hist) {
    int pos = blockIdx.x * blockDim.x + threadIdx.x;  // over BATCH*FH*FW
    if (pos >= BATCH * FHh * FWw) return;
    int b = pos / (FHh * FWw);
    const float2* in2 = (const float2*)(labels + (size_t)pos * NA);
    float v[NA];
    float2 p0 = in2[0], p1 = in2[1], p2 = in2[2];
    v[0] = p0.x; v[1] = p0.y; v[2] = p1.x; v[3] = p1.y; v[4] = p2.x; v[5] = p2.y;
    float m = v[0];
#pragma unroll
    for (int a = 1; a < NA; ++a) m = fmaxf(m, v[a]);
    float s = 0.0f;
#pragma unroll
    for (int a = 0; a < NA; ++a) { v[a] = expf(v[a] - m); s += v[a]; }
    float inv = 1.0f / s;
    float2* o2 = (float2*)(scores + (size_t)pos * NA);
    unsigned int* hb = hist + (size_t)b * NBIN;
#pragma unroll
    for (int a = 0; a < NA; ++a) v[a] *= inv;
    o2[0] = make_float2(v[0], v[1]);
    o2[1] = make_float2(v[2], v[3]);
    o2[2] = make_float2(v[4], v[5]);
#pragma unroll
    for (int a = 0; a < NA; ++a)
        atomicAdd(&hb[__float_as_uint(v[a]) >> 16], 1u);  // fire-and-forget
}

// ---------------- K2: per-batch find 16-bit cutoff bin ----------------
__global__ __launch_bounds__(1024) void k_cut(const unsigned int* __restrict__ hist,
                                              unsigned int* __restrict__ cut) {
    const int b = blockIdx.x;
    const int tid = threadIdx.x;
    const unsigned int* h = hist + (size_t)b * NBIN;
    const int blk0 = NBIN - 64 * (tid + 1);
    const uint4* h4 = (const uint4*)(h + blk0);
    unsigned int s = 0;
#pragma unroll
    for (int k = 0; k < 16; ++k) {
        uint4 q = h4[k];
        s += q.x + q.y + q.z + q.w;
    }
    const int lane = tid & 63, wid = tid >> 6;
    unsigned int inc = s;
#pragma unroll
    for (int d = 1; d < 64; d <<= 1) {
        unsigned int v = __shfl_up(inc, d);
        if (lane >= d) inc += v;
    }
    __shared__ unsigned int wtot[16];
    if (lane == 63) wtot[wid] = inc;
    __syncthreads();
    unsigned int woff = 0;
    for (int w = 0; w < 16; ++w) if (w < wid) woff += wtot[w];
    unsigned int excl = woff + inc - s;  // count strictly above this block
    if (excl < PRE_K && excl + s >= PRE_K) {
        const int base = NBIN - 1 - tid * 64;  // top bin of the block
        unsigned int run = excl;
        for (int k = 0; k < 64; ++k) {
            run += h[base - k];
            if (run >= PRE_K) { cut[b * 16] = (unsigned int)(base - k); break; }
        }
    }
}

// ------- K3: atomic-free gather. block = (batch b, segment kb of 256 anchors) -
__global__ __launch_bounds__(256) void k_gather(
        const float* __restrict__ scores, const unsigned int* __restrict__ cut,
        u64* __restrict__ cand, unsigned int* __restrict__ counts) {
    const int blk = blockIdx.x;
    const int b = blk / SEGS, kb = blk - b * SEGS;
    const int tid = threadIdx.x;
    __shared__ unsigned int s_cut;
    __shared__ unsigned int s_wcnt[4];
    if (tid == 0) s_cut = cut[b * 16];
    __syncthreads();
    const int idx = kb * 256 + tid;                       // batch-local anchor
    const unsigned int bits = __float_as_uint(scores[(size_t)b * NANCH + idx]);
    const bool pass = (bits >> 16) >= s_cut;
    const u64 m = __ballot(pass);
    const int lane = tid & 63, w = tid >> 6;
    if (lane == 0) s_wcnt[w] = (unsigned int)__popcll(m);
    __syncthreads();
    unsigned int pre = 0, tot = 0;
#pragma unroll
    for (int i = 0; i < 4; ++i) { unsigned int c = s_wcnt[i]; if (i < w) pre += c; tot += c; }
    if (pass) {
        unsigned int rank = pre + (unsigned int)__popcll(m & ((1ull << lane) - 1ull));
        cand[((size_t)b * SEGS + kb) * 256 + rank] =
            ((u64)bits << 32) | (unsigned int)(~idx);
    }
    if (tid == 0) counts[b * SEGS + kb] = tot;
}

// ---- K4: exact rank select (counting sort) + decode top-2000 ----------------
// grid (NSLICE, BATCH), 256 threads. Each block compacts the segmented
// candidates into LDS, then each thread ranks ONE candidate against all n
// (broadcast LDS reads) and decodes directly to pre_boxes[rank].
__global__ __launch_bounds__(256) void k_rank(
        const u64* __restrict__ cand, const unsigned int* __restrict__ counts,
        const float* __restrict__ deltas, const float* __restrict__ anchors,
        float4* __restrict__ pre_boxes, float* __restrict__ pre_scores) {
    const int b = blockIdx.y;
    const int slice = blockIdx.x;
    const int tid = threadIdx.x;
    __shared__ u64 skey[CAND_CAP];
    __shared__ unsigned int s_wsum[4];

    // zero-pad (so the j-loop can run in multiples of 8; real keys never 0)
    for (int i = tid; i < CAND_CAP; i += 256) skey[i] = 0ull;

    // scan the 192 per-segment counts (4 waves; wave 3 all-zero)
    unsigned int v = (tid < SEGS) ? counts[b * SEGS + tid] : 0u;
    const int lane = tid & 63, wid = tid >> 6;
    unsigned int inc = v;
#pragma unroll
    for (int d = 1; d < 64; d <<= 1) {
        unsigned int t = __shfl_up(inc, d);
        if (lane >= d) inc += t;
    }
    if (lane == 63) s_wsum[wid] = inc;
    __syncthreads();   // covers zero-fill + s_wsum
    unsigned int woff = 0;
#pragma unroll
    for (int i = 0; i < 4; ++i) if (i < wid) woff += s_wsum[i];
    if (tid < SEGS) {
        unsigned int off = woff + inc - v;  // exclusive prefix
        const u64* seg = cand + ((size_t)b * SEGS + tid) * 256;
        for (unsigned int k = 0; k < v; ++k) {
            unsigned int p = off + k;
            if (p < CAND_CAP) skey[p] = seg[k];
        }
    }
    __syncthreads();
    int n = (int)(s_wsum[0] + s_wsum[1] + s_wsum[2] + s_wsum[3]);
    if (n > CAND_CAP) n = CAND_CAP;

    const int ci = slice * 256 + tid;
    const u64 mykey = (ci < n) ? skey[ci] : 0ull;

    // exact descending rank: count keys strictly greater (keys distinct;
    // zero-padding never counts since real keys are nonzero and > 0)
    int rank = 0;
    const int n8 = (n + 7) & ~7;
#pragma unroll 1
    for (int j = 0; j < n8; j += 8) {
        u64 k0 = skey[j + 0], k1 = skey[j + 1], k2 = skey[j + 2], k3 = skey[j + 3];
        u64 k4 = skey[j + 4], k5 = skey[j + 5], k6 = skey[j + 6], k7 = skey[j + 7];
        rank += (k0 > mykey) + (k1 > mykey) + (k2 > mykey) + (k3 > mykey)
              + (k4 > mykey) + (k5 > mykey) + (k6 > mykey) + (k7 > mykey);
    }

    if (ci < n && rank < PRE_K) {
        u64 key = mykey;
        int idx = (int)(~(unsigned int)key);
        float score = __uint_as_float((unsigned int)(key >> 32));
        const float* anc = anchors + (size_t)idx * 4;
        const float* del = deltas + ((size_t)b * NANCH + idx) * 4;
        float a0 = anc[0], a1 = anc[1], a2 = anc[2], a3 = anc[3];
        float ah = a2 - a0, aw = a3 - a1;
        float acy = a0 + 0.5f * ah, acx = a1 + 0.5f * aw;
        float d0 = del[0] * 0.1f, d1 = del[1] * 0.1f;
        float d2 = del[2] * 0.2f, d3 = del[3] * 0.2f;
        float bh = expf(d2) * ah, bw = expf(d3) * aw;
        float bcy = d0 * ah + acy, bcx = d1 * aw + acx;
        float y1 = bcy - 0.5f * bh, x1 = bcx - 0.5f * bw;
        pre_boxes[(size_t)b * PRE_K + rank] = make_float4(y1, x1, y1 + bh, x1 + bw);
        pre_scores[(size_t)b * PRE_K + rank] = score;
    }
}

// ---------------- K5: suppression bit-matrix (LDS-staged cols) ----------------
__global__ __launch_bounds__(64) void k_iou(const float4* __restrict__ pre_boxes,
                                            u64* __restrict__ supp) {
    const int cb = blockIdx.x;   // col word 0..31
    const int rb = blockIdx.y;   // row block 0..31
    const int b  = blockIdx.z;
    const int lane = threadIdx.x;
    const int i = rb * 64 + lane;
    const int j0 = cb * 64;
    if (cb < rb) {
        if (i < PRE_K) supp[((size_t)b * PRE_K + i) * 32 + cb] = 0ull;
        return;
    }
    __shared__ float4 sbox[64];
    const float4* boxes = pre_boxes + (size_t)b * PRE_K;
    int j = j0 + lane;
    sbox[lane] = (j < PRE_K) ? boxes[j] : make_float4(0.f, 0.f, 0.f, 0.f);
    __syncthreads();
    if (i >= PRE_K) return;
    float4 bi = boxes[i];
    float area_i = (bi.z - bi.x) * (bi.w - bi.y);
    u64 bits = 0ull;
    const int tmax = (PRE_K - j0 < 64) ? (PRE_K - j0) : 64;
    for (int t = 0; t < tmax; ++t) {
        int jj = j0 + t;
        if (jj <= i) continue;
        float4 bj = sbox[t];
        float iy1 = fmaxf(bi.x, bj.x), ix1 = fmaxf(bi.y, bj.y);
        float iy2 = fminf(bi.z, bj.z), ix2 = fminf(bi.w, bj.w);
        float inter = fmaxf(iy2 - iy1, 0.0f) * fmaxf(ix2 - ix1, 0.0f);
        float area_j = (bj.z - bj.x) * (bj.w - bj.y);
        float uni = area_i + area_j - inter;
        float iou = inter / fmaxf(uni, 1e-8f);
        if (iou > 0.7f) bits |= (1ull << t);
    }
    supp[((size_t)b * PRE_K + i) * 32 + cb] = bits;
}

// ---------------- K6: serial greedy reduce + compact + outputs ----------------
// Async LDS double-buffer via global_load_lds + counted vmcnt. Exact early
// exit: once >=POST_K rows are kept, later rows cannot affect the output.
__device__ __forceinline__ u64 readlane64(u64 x, int ln) {
    unsigned int lo = __builtin_amdgcn_readlane((unsigned int)x, ln);
    unsigned int hi = __builtin_amdgcn_readlane((unsigned int)(x >> 32), ln);
    return ((u64)hi << 32) | (u64)lo;
}

// returns the final keep mask (cur) of word wi — wave-uniform, exact
template <int ROWS>
__device__ __forceinline__ u64 proc_epoch(const u64* __restrict__ bufp, int wi,
                                          int p, int w, u64& r0, u64& r1) {
    u64 acc = r0 | r1;
    u64 cur = ~(readlane64(acc, wi) | readlane64(acc, 32 + wi));
#pragma unroll
    for (int g = 0; g < ROWS / 16; ++g) {
        u64 ld[8];
#pragma unroll
        for (int k = 0; k < 8; ++k)
            ld[k] = bufp[(g * 16 + 2 * k + p) * 32 + w];
        u64 t0 = (ld[0] | ld[1]) | (ld[2] | ld[3]);
        u64 t1 = (ld[4] | ld[5]) | (ld[6] | ld[7]);
        u64 tor = t0 | t1;
        u64 intra = readlane64(tor, wi) | readlane64(tor, 32 + wi);
        if (intra == 0ull) {
#pragma unroll
            for (int k = 0; k < 8; ++k) {
                int bitpos = g * 16 + 2 * k + p;   // per-lane (parity)
                u64 msk = ((cur >> bitpos) & 1ull) ? ~0ull : 0ull;
                if (k & 1) r1 |= ld[k] & msk; else r0 |= ld[k] & msk;
            }
        } else {
#pragma unroll
            for (int c = 0; c < 16; ++c) {
                const int pi = c & 1, k = c >> 1;
                if ((cur >> (g * 16 + c)) & 1ull) {
                    cur &= ~readlane64(ld[k], pi * 32 + wi);
                    u64 msk = (p == pi) ? ~0ull : 0ull;
                    if (k & 1) r1 |= ld[k] & msk; else r0 |= ld[k] & msk;
                }
            }
        }
    }
    return cur;
}

__global__ __launch_bounds__(64) void k_final(const u64* __restrict__ supp,
                        const float4* __restrict__ pre_boxes,
                        const float* __restrict__ pre_scores,
                        float* __restrict__ out) {
    const int b = blockIdx.x;
    const int l = threadIdx.x;
    const int p = l >> 5, w = l & 31;
    float* ob = out + (size_t)b * POST_K * 4;
    float* os = out + (size_t)BATCH * POST_K * 4 + (size_t)b * POST_K;
    for (int t = l; t < POST_K * 4; t += 64) ob[t] = 0.0f;
    for (int t = l; t < POST_K; t += 64) os[t] = 0.0f;
    // drain stores so counted vmcnt below only sees staging loads
    asm volatile("s_waitcnt vmcnt(0)" ::: "memory");

    __shared__ u64 sbuf[2][2048];   // 2 x 16KB epoch buffers
    const char* Sb = (const char*)(supp + (size_t)b * PRE_K * 32);

#define ISSUE_EPOCH(ep, nchunks)                                              \
    do {                                                                      \
        const char* gsrc_ = Sb + (size_t)(ep) * 16384 + (size_t)l * 16;       \
        char* ldst_ = (char*)&sbuf[(ep) & 1][0];                              \
        _Pragma("unroll")                                                     \
        for (int k_ = 0; k_ < (nchunks); ++k_)                                \
            __builtin_amdgcn_global_load_lds(                                 \
                (const __attribute__((address_space(1))) void*)(gsrc_ + k_ * 1024), \
                (__attribute__((address_space(3))) void*)(ldst_ + k_ * 1024), \
                16, 0, 0);                                                    \
    } while (0)

    u64 r0 = 0ull, r1 = 0ull;
    int kept = 0;
    ISSUE_EPOCH(0, 16);
    for (int e = 0; e < 32; ++e) {
        if (e < 30) {
            ISSUE_EPOCH(e + 1, 16);
            asm volatile("s_waitcnt vmcnt(16)" ::: "memory");  // epoch e landed
        } else if (e == 30) {
            ISSUE_EPOCH(31, 4);                                // tail: 16 rows
            asm volatile("s_waitcnt vmcnt(4)" ::: "memory");   // epoch 30 landed
        } else {
            asm volatile("s_waitcnt vmcnt(0)" ::: "memory");   // tail landed
        }
        __builtin_amdgcn_sched_barrier(0);
        u64 curf;
        if (e < 31) curf = proc_epoch<64>(&sbuf[e & 1][0], e, p, w, r0, r1);
        else        curf = proc_epoch<16>(&sbuf[e & 1][0], e, p, w, r0, r1) & 0xFFFFull;
        kept += __builtin_popcountll(curf);   // wave-uniform
        if (kept >= POST_K) break;            // exact: later rows can't matter
    }
    asm volatile("s_waitcnt vmcnt(0)" ::: "memory");  // drain in-flight prefetch
#undef ISSUE_EPOCH

    // merge parity halves: removed word w = lane(w) | lane(w+32)
    u64 full = r0 | r1;
    u64 oth = __shfl(full, w + 32);
    u64 kw = ~(full | oth);
    if (w == 31) kw &= 0xFFFFull;  // rows 1984..1999 only
    int cnt = (l < 32) ? __builtin_popcountll(kw) : 0;
    int cum = cnt;
#pragma unroll
    for (int d = 1; d < 64; d <<= 1) {
        int v = __shfl_up(cum, d);
        if (l >= d) cum += v;
    }
    int r = cum - cnt;
    __syncthreads();
    if (l < 32) {
        u64 m = kw;
        while (m != 0ull && r < POST_K) {
            int t = __builtin_ctzll(m);
            m &= m - 1ull;
            int i = w * 64 + t;
            float4 bx = pre_boxes[(size_t)b * PRE_K + i];
            ob[r * 4 + 0] = fminf(fmaxf(bx.x, 0.0f), 1.0f);
            ob[r * 4 + 1] = fminf(fmaxf(bx.y, 0.0f), 1.0f);
            ob[r * 4 + 2] = fminf(fmaxf(bx.z, 0.0f), 1.0f);
            ob[r * 4 + 3] = fminf(fmaxf(bx.w, 0.0f), 1.0f);
            os[r] = pre_scores[(size_t)b * PRE_K + i];
            ++r;
        }
    }
}

extern "C" void kernel_launch(void* const* d_in, const int* in_sizes, int n_in,
                              void* d_out, int out_size, void* d_ws, size_t ws_size,
                              hipStream_t stream) {
    const float* deltas  = (const float*)d_in[0];
    const float* labels  = (const float*)d_in[1];
    const float* anchors = (const float*)d_in[2];
    float* out = (float*)d_out;

    char* ws = (char*)d_ws;
    float* scores          = (float*)(ws + WS_SC);
    unsigned int* hist     = (unsigned int*)(ws + WS_A);
    u64* cd                = (u64*)(ws + WS_A);   // reuses hist
    u64* sp                = (u64*)(ws + WS_A);   // reuses cand
    unsigned int* cntp     = (unsigned int*)(ws + WS_CNT);
    unsigned int* cutp     = (unsigned int*)(ws + WS_CUT);
    float4* pre_boxes      = (float4*)(ws + WS_PB);              // reuses scores
    float* pre_scores      = (float*)(ws + WS_PS);

    k_zero<<<(BATCH * NBIN + 255) / 256, 256, 0, stream>>>(hist);
    k_softhist<<<(BATCH * FHh * FWw + 255) / 256, 256, 0, stream>>>(labels, scores, hist);
    k_cut<<<BATCH, 1024, 0, stream>>>(hist, cutp);
    k_gather<<<BATCH * SEGS, 256, 0, stream>>>(scores, cutp, cd, cntp);
    k_rank<<<dim3(NSLICE, BATCH), 256, 0, stream>>>(cd, cntp, deltas, anchors, pre_boxes, pre_scores);
    k_iou<<<dim3(32, 32, BATCH), 64, 0, stream>>>(pre_boxes, sp);
    k_final<<<BATCH, 64, 0, stream>>>(sp, pre_boxes, pre_scores, out);
}